// Round 5
// baseline (109.722 us; speedup 1.0000x reference)
//
#include <hip/hip_runtime.h>
#include <cstddef>

using bf16x8  = __attribute__((ext_vector_type(8))) short;
using f32x4   = __attribute__((ext_vector_type(4))) float;

__device__ __forceinline__ float exp2_f(float x){ float r; asm("v_exp_f32 %0, %1" : "=v"(r) : "v"(x)); return r; }
__device__ __forceinline__ float rcp_f (float x){ float r; asm("v_rcp_f32 %0, %1" : "=v"(r) : "v"(x)); return r; }
__device__ __forceinline__ unsigned pk2(float lo, float hi){
  unsigned r; asm("v_cvt_pk_bf16_f32 %0, %1, %2" : "=v"(r) : "v"(lo), "v"(hi)); return r;
}

// problem sizes: B=8 Q=16 KV=2048 NQ=NK=NV=H=512
#define SCALE_2LOG2E 2.885390081777927f   // 2*log2(e): exp2(x*S) = exp(2x)
#define EKS 132                           // ek LDS row stride (f32): conflict-free

// workspace layout (bytes); total = 22,282,240
#define OFF_EQB       0u          // 128x512 f32: exp2(S*q_part)
#define OFF_EPART     262144u     // 4 x [8*2048*16] f32 partial logits
#define OFF_SC        4456448u    // 8x2048x16 f32 scores
#define OFF_PART      5505024u    // 8x64x16x512 f32 partial outputs

// Shared GEMM tile machinery: 128x128 tile, K=512, BK=32, reg-staged f32->bf16.
// LDS tiles [128][32] shorts with 16B-chunk XOR swizzle: chunk' = chunk ^ ((row>>1)&3).
// Per thread per kt: 4+4 float4 global loads, 8 cvt_pk, 4+4 ds_write_b64;
// fragment reads: 8 ds_read_b128, banks verified conflict-free.

// ---------------- K1: q-GEMM: eqb = exp2(S * query·Wq^T) ------------------
__global__ __launch_bounds__(256) void k_qgemm(
    const float* __restrict__ query, const float* __restrict__ W,
    float* __restrict__ eqb)
{
  __shared__ struct { short A[128*32]; short B[128*32]; } g;
  const int tid = threadIdx.x;
  const int l = tid & 63, w = tid >> 6;
  const int n0 = blockIdx.x * 128;

  f32x4 acc[4][4];
  #pragma unroll
  for (int i = 0; i < 4; ++i)
    #pragma unroll
    for (int j = 0; j < 4; ++j) acc[i][j] = (f32x4){0.f,0.f,0.f,0.f};

  float4 areg[4], breg[4];
  auto gload = [&](int kt) {
    const int k0 = kt * 32;
    #pragma unroll
    for (int m = 0; m < 4; ++m) {
      const int f = tid * 4 + m * 1024;
      const int row = f >> 5, col = f & 31;
      areg[m] = *(const float4*)(query + (size_t)row * 512 + k0 + col);
      breg[m] = *(const float4*)(W + (size_t)(n0 + row) * 1024 + k0 + col);
    }
  };
  auto dswrite = [&]() {
    #pragma unroll
    for (int m = 0; m < 4; ++m) {
      const int f = tid * 4 + m * 1024;
      const int row = f >> 5, col = f & 31;
      const int o = row * 32 + (((col >> 3) ^ ((row >> 1) & 3)) << 3) + (col & 7);
      *(uint2*)&g.A[o] = make_uint2(pk2(areg[m].x, areg[m].y), pk2(areg[m].z, areg[m].w));
      *(uint2*)&g.B[o] = make_uint2(pk2(breg[m].x, breg[m].y), pk2(breg[m].z, breg[m].w));
    }
  };
  const int wm = w >> 1, wn = w & 1;
  const int fr = l & 15, fg = l >> 4;
  auto compute = [&]() {
    bf16x8 af[4], bfv[4];
    #pragma unroll
    for (int i = 0; i < 4; ++i) {
      const int ar = wm*64 + i*16 + fr;
      af[i]  = *(const bf16x8*)&g.A[ar*32 + ((fg ^ ((ar>>1)&3)) << 3)];
      const int br = wn*64 + i*16 + fr;
      bfv[i] = *(const bf16x8*)&g.B[br*32 + ((fg ^ ((br>>1)&3)) << 3)];
    }
    #pragma unroll
    for (int i = 0; i < 4; ++i)
      #pragma unroll
      for (int j = 0; j < 4; ++j)
        acc[i][j] = __builtin_amdgcn_mfma_f32_16x16x32_bf16(af[i], bfv[j], acc[i][j], 0, 0, 0);
  };

  gload(0);
  dswrite();
  for (int kt = 0; kt < 16; ++kt) {
    __syncthreads();
    if (kt < 15) gload(kt + 1);
    compute();
    __syncthreads();
    if (kt < 15) dswrite();
  }
  #pragma unroll
  for (int j = 0; j < 4; ++j) {
    const int gh = n0 + wn*64 + j*16 + fr;
    #pragma unroll
    for (int i = 0; i < 4; ++i)
      #pragma unroll
      for (int r = 0; r < 4; ++r) {
        const int gm = wm*64 + i*16 + fg*4 + r;
        eqb[gm * 512 + gh] = exp2_f(acc[i][j][r] * SCALE_2LOG2E);
      }
  }
}

// ---------------- K2: FUSED k-GEMM + energy -------------------------------
// block (by, hc): 128x128 GEMM (keys f32 reg-staged), ek half-tiles in LDS,
// energy e_part[hc][row][q] = sum_h vv_h / (1 + ek*eq).
struct FusedSM {
  union {
    struct { short A[128*32]; short B[128*32]; } g;   // 16 KB
    float ek[64 * EKS];                               // 33.8 KB
  } u;
  float eqs[16 * 128];                                // 8 KB
};

__global__ __launch_bounds__(256, 3) void k_fused(
    const float* __restrict__ keys, const float* __restrict__ W,
    const float* __restrict__ w_bias, const float* __restrict__ eqb,
    const float* __restrict__ vw, float* __restrict__ e_part)
{
  __shared__ FusedSM sm;
  const int tid = threadIdx.x;
  const int l = tid & 63, w = tid >> 6;
  const int by = blockIdx.x;              // 0..127 m-tile (128 k-rows)
  const int hc = blockIdx.y;              // 0..3 h-chunk
  const int h0 = hc * 128;
  const int b  = by >> 4;

  // stage eqs [16 q][128 h] early (region disjoint from staging/ek)
  {
    const int q = tid >> 4, c0 = (tid & 15) * 8;
    const float* src = eqb + (size_t)(b * 16 + q) * 512 + h0 + c0;
    *(float4*)&sm.eqs[q * 128 + c0]     = *(const float4*)src;
    *(float4*)&sm.eqs[q * 128 + c0 + 4] = *(const float4*)(src + 4);
  }

  const float* Abase = keys + (size_t)by * 128 * 512;
  const float* Bbase = W + (size_t)h0 * 1024 + 512;   // Wk = W[:, 512:]

  f32x4 acc[4][4];
  #pragma unroll
  for (int i = 0; i < 4; ++i)
    #pragma unroll
    for (int j = 0; j < 4; ++j) acc[i][j] = (f32x4){0.f,0.f,0.f,0.f};

  float4 areg[4], breg[4];
  auto gload = [&](int kt) {
    const int k0 = kt * 32;
    #pragma unroll
    for (int m = 0; m < 4; ++m) {
      const int f = tid * 4 + m * 1024;
      const int row = f >> 5, col = f & 31;
      areg[m] = *(const float4*)(Abase + (size_t)row * 512 + k0 + col);
      breg[m] = *(const float4*)(Bbase + (size_t)row * 1024 + k0 + col);
    }
  };
  auto dswrite = [&]() {
    #pragma unroll
    for (int m = 0; m < 4; ++m) {
      const int f = tid * 4 + m * 1024;
      const int row = f >> 5, col = f & 31;
      const int o = row * 32 + (((col >> 3) ^ ((row >> 1) & 3)) << 3) + (col & 7);
      *(uint2*)&sm.u.g.A[o] = make_uint2(pk2(areg[m].x, areg[m].y), pk2(areg[m].z, areg[m].w));
      *(uint2*)&sm.u.g.B[o] = make_uint2(pk2(breg[m].x, breg[m].y), pk2(breg[m].z, breg[m].w));
    }
  };
  const int wm = w >> 1, wn = w & 1;
  const int fr = l & 15, fg = l >> 4;
  auto compute = [&]() {
    bf16x8 af[4], bfv[4];
    #pragma unroll
    for (int i = 0; i < 4; ++i) {
      const int ar = wm*64 + i*16 + fr;
      af[i]  = *(const bf16x8*)&sm.u.g.A[ar*32 + ((fg ^ ((ar>>1)&3)) << 3)];
      const int br = wn*64 + i*16 + fr;
      bfv[i] = *(const bf16x8*)&sm.u.g.B[br*32 + ((fg ^ ((br>>1)&3)) << 3)];
    }
    #pragma unroll
    for (int i = 0; i < 4; ++i)
      #pragma unroll
      for (int j = 0; j < 4; ++j)
        acc[i][j] = __builtin_amdgcn_mfma_f32_16x16x32_bf16(af[i], bfv[j], acc[i][j], 0, 0, 0);
  };

  gload(0);
  dswrite();
  for (int kt = 0; kt < 16; ++kt) {
    __syncthreads();                 // tile kt visible
    if (kt < 15) gload(kt + 1);      // loads in flight under compute
    compute();
    __syncthreads();                 // reads of tile kt done
    if (kt < 15) dswrite();
  }

  // v weights (pre-scaled by -2); lane owns h-cols {s*32+g*4+t, s*32+16+g*4+t}
  const int g = l & 3, kl = l >> 2;
  float vv[32];
  #pragma unroll
  for (int s = 0; s < 4; ++s) {
    const float4 a0 = *(const float4*)(vw + h0 + s*32 + g*4);
    const float4 a1 = *(const float4*)(vw + h0 + s*32 + 16 + g*4);
    vv[s*8+0]=-2.f*a0.x; vv[s*8+1]=-2.f*a0.y; vv[s*8+2]=-2.f*a0.z; vv[s*8+3]=-2.f*a0.w;
    vv[s*8+4]=-2.f*a1.x; vv[s*8+5]=-2.f*a1.y; vv[s*8+6]=-2.f*a1.z; vv[s*8+7]=-2.f*a1.w;
  }

  // energy in two 64-row halves: waves with wm==half dump their acc quadrants
  // (ek = exp2(S*(k_part+bias))) into [64][EKS] LDS, then all waves consume.
  #pragma unroll
  for (int half = 0; half < 2; ++half) {
    if (wm == half) {
      #pragma unroll
      for (int j = 0; j < 4; ++j) {
        const int lc = wn*64 + j*16 + fr;
        const float bias = w_bias[h0 + lc];
        #pragma unroll
        for (int i = 0; i < 4; ++i)
          #pragma unroll
          for (int r = 0; r < 4; ++r)
            sm.u.ek[(i*16 + fg*4 + r) * EKS + lc] = exp2_f((acc[i][j][r] + bias) * SCALE_2LOG2E);
      }
    }
    __syncthreads();

    const int lr = w * 16 + kl;                   // local row within half
    float ek[32];
    #pragma unroll
    for (int s = 0; s < 4; ++s) {
      *(float4*)&ek[s*8]     = *(const float4*)&sm.u.ek[lr*EKS + s*32 + g*4];
      *(float4*)&ek[s*8 + 4] = *(const float4*)&sm.u.ek[lr*EKS + s*32 + 16 + g*4];
    }
    const size_t epbase = (size_t)hc * 262144 + ((size_t)(by * 128 + half * 64 + lr)) * 16;
    #pragma unroll 2
    for (int q = 0; q < 16; ++q) {
      float a0 = 0.f, a1 = 0.f;
      #pragma unroll
      for (int s = 0; s < 4; ++s) {
        const float* er = &sm.eqs[q * 128 + s * 32 + g * 4];
        const float4 E0 = *(const float4*)er;
        const float4 E1 = *(const float4*)(er + 16);
        a0 = fmaf(vv[s*8+0], rcp_f(fmaf(ek[s*8+0], E0.x, 1.f)), a0);
        a1 = fmaf(vv[s*8+1], rcp_f(fmaf(ek[s*8+1], E0.y, 1.f)), a1);
        a0 = fmaf(vv[s*8+2], rcp_f(fmaf(ek[s*8+2], E0.z, 1.f)), a0);
        a1 = fmaf(vv[s*8+3], rcp_f(fmaf(ek[s*8+3], E0.w, 1.f)), a1);
        a0 = fmaf(vv[s*8+4], rcp_f(fmaf(ek[s*8+4], E1.x, 1.f)), a0);
        a1 = fmaf(vv[s*8+5], rcp_f(fmaf(ek[s*8+5], E1.y, 1.f)), a1);
        a0 = fmaf(vv[s*8+6], rcp_f(fmaf(ek[s*8+6], E1.z, 1.f)), a0);
        a1 = fmaf(vv[s*8+7], rcp_f(fmaf(ek[s*8+7], E1.w, 1.f)), a1);
      }
      float a = a0 + a1;
      a += __shfl_xor(a, 1, 64);
      a += __shfl_xor(a, 2, 64);
      if (g == 0) e_part[epbase + q] = a;
    }
    if (half == 0) __syncthreads();   // reads done before half-1 overwrites
  }
}

// ---------------- K3: softmax over k: sum 4 partials, normalize -----------
__global__ __launch_bounds__(256) void k_softmax(
    const float* __restrict__ e_part, float* __restrict__ sc)
{
  const int b = blockIdx.x >> 4, q = blockIdx.x & 15;
  const int base = b * 32768 + q;           // stride 16 over k
  const int tid = threadIdx.x;
  __shared__ float redm[4], reds[4];

  float vals[8];
  float mx = -1e30f;
  #pragma unroll
  for (int i = 0; i < 8; ++i) {
    const int x = base + (tid + i * 256) * 16;
    vals[i] = (e_part[x] + e_part[x + 262144]) + (e_part[x + 524288] + e_part[x + 786432]);
    mx = fmaxf(mx, vals[i]);
  }
  #pragma unroll
  for (int msk = 1; msk < 64; msk <<= 1) mx = fmaxf(mx, __shfl_xor(mx, msk, 64));
  if ((tid & 63) == 0) redm[tid >> 6] = mx;
  __syncthreads();
  mx = fmaxf(fmaxf(redm[0], redm[1]), fmaxf(redm[2], redm[3]));

  float ex[8], sum = 0.f;
  #pragma unroll
  for (int i = 0; i < 8; ++i) { ex[i] = __expf(vals[i] - mx); sum += ex[i]; }
  #pragma unroll
  for (int msk = 1; msk < 64; msk <<= 1) sum += __shfl_xor(sum, msk, 64);
  if ((tid & 63) == 0) reds[tid >> 6] = sum;
  __syncthreads();
  sum = reds[0] + reds[1] + reds[2] + reds[3];
  const float r = 1.f / sum;
  #pragma unroll
  for (int i = 0; i < 8; ++i) sc[base + (tid + i * 256) * 16] = ex[i] * r;
}

// ---------------- K4: partial PV (64 chunks of 32 k) ----------------------
__global__ __launch_bounds__(256) void k_pv(
    const float* __restrict__ values, const float* __restrict__ sc,
    float* __restrict__ part)
{
  __shared__ float s_sc[64 * 16];
  const int c = blockIdx.x, b = blockIdx.y;   // c: 32 blocks of 64 k
  const int tid = threadIdx.x;
  const float* ssrc = sc + (b * 2048 + c * 64) * 16;
  *(float4*)&s_sc[tid * 4] = *(const float4*)&ssrc[tid * 4];
  __syncthreads();

  const int kg = tid >> 7, nt = tid & 127;    // 2 k-groups x 128 n-slots
  float4 acc[16];
  #pragma unroll
  for (int q = 0; q < 16; ++q) acc[q] = make_float4(0.f, 0.f, 0.f, 0.f);

  const float* vbase = values + ((size_t)(b * 2048 + c * 64 + kg * 32)) * 512 + nt * 4;
  #pragma unroll 2
  for (int kk = 0; kk < 32; ++kk) {
    const float4 v4 = *(const float4*)(vbase + (size_t)kk * 512);
    const int ks = (kg * 32 + kk) * 16;
    #pragma unroll
    for (int g = 0; g < 4; ++g) {
      const float4 s4 = *(const float4*)&s_sc[ks + g * 4];
      #define PV_ACC(qi, sv) { float4& a = acc[qi]; a.x += v4.x*(sv); a.y += v4.y*(sv); a.z += v4.z*(sv); a.w += v4.w*(sv); }
      PV_ACC(g*4+0, s4.x); PV_ACC(g*4+1, s4.y); PV_ACC(g*4+2, s4.z); PV_ACC(g*4+3, s4.w);
      #undef PV_ACC
    }
  }
  const int cc = c * 2 + kg;                  // 64 chunks
  float* pbase = part + ((size_t)((b * 64 + cc) * 16)) * 512 + nt * 4;
  #pragma unroll
  for (int q = 0; q < 16; ++q) *(float4*)(pbase + q * 512) = acc[q];
}

// ---------------- K5: reduce 64 chunks -> out[b,q,n] ----------------------
__global__ __launch_bounds__(256) void k_reduce(
    const float* __restrict__ part, float* __restrict__ out)
{
  const int o = blockIdx.x * 256 + threadIdx.x;   // < 65536
  const int n = o & 511;
  const int q = (o >> 9) & 15;
  const int b = o >> 13;
  const float* p = part + ((size_t)(b * 64 * 16 + q)) * 512 + n;
  float s = 0.f;
  #pragma unroll
  for (int cc = 0; cc < 64; ++cc) s += p[(size_t)cc * 16 * 512];
  out[o] = s;
}

extern "C" void kernel_launch(void* const* d_in, const int* in_sizes, int n_in,
                              void* d_out, int out_size, void* d_ws, size_t ws_size,
                              hipStream_t stream)
{
  const float* query  = (const float*)d_in[0];
  const float* keys   = (const float*)d_in[1];
  const float* values = (const float*)d_in[2];
  const float* W      = (const float*)d_in[3];
  const float* w_bias = (const float*)d_in[4];
  const float* vw     = (const float*)d_in[5];
  // d_in[6] (v_bias) + sum_h v_h are (k)-constant logit shifts -> softmax-invariant.

  char* ws = (char*)d_ws;
  float* eqb    = (float*)(ws + OFF_EQB);
  float* e_part = (float*)(ws + OFF_EPART);
  float* sc     = (float*)(ws + OFF_SC);
  float* part   = (float*)(ws + OFF_PART);

  hipLaunchKernelGGL(k_qgemm, dim3(4), dim3(256), 0, stream, query, W, eqb);
  hipLaunchKernelGGL(k_fused, dim3(128, 4), dim3(256), 0, stream,
                     keys, W, w_bias, eqb, vw, e_part);
  hipLaunchKernelGGL(k_softmax, dim3(128), dim3(256), 0, stream, e_part, sc);
  hipLaunchKernelGGL(k_pv, dim3(32, 8), dim3(256), 0, stream, values, sc, part);
  hipLaunchKernelGGL(k_reduce, dim3(256), dim3(256), 0, stream, part, (float*)d_out);
}

// Round 6
// 104.574 us; speedup vs baseline: 1.0492x; 1.0492x over previous
//
#include <hip/hip_runtime.h>
#include <cstddef>

using bf16x8  = __attribute__((ext_vector_type(8))) short;
using f32x4   = __attribute__((ext_vector_type(4))) float;
using ushort8 = __attribute__((ext_vector_type(8))) unsigned short;

#define GLL16(gp, lp) __builtin_amdgcn_global_load_lds( \
    (const __attribute__((address_space(1))) unsigned int*)(const void*)(gp), \
    (__attribute__((address_space(3))) unsigned int*)(void*)(lp), 16, 0, 0)

__device__ __forceinline__ float exp2_f(float x){ float r; asm("v_exp_f32 %0, %1" : "=v"(r) : "v"(x)); return r; }
__device__ __forceinline__ float rcp_f (float x){ float r; asm("v_rcp_f32 %0, %1" : "=v"(r) : "v"(x)); return r; }
__device__ __forceinline__ unsigned pk2(float lo, float hi){
  unsigned r; asm("v_cvt_pk_bf16_f32 %0, %1, %2" : "=v"(r) : "v"(lo), "v"(hi)); return r;
}
__device__ __forceinline__ unsigned short f2bf(float f){
  unsigned int u = __float_as_uint(f);
  u = u + 0x7FFFu + ((u >> 16) & 1u);
  return (unsigned short)(u >> 16);
}

// problem sizes: B=8 Q=16 KV=2048 NQ=NK=NV=H=512
#define KEYS_N   8388608
#define SCALE_2LOG2E 2.885390081777927f   // 2*log2(e): exp2(x*S) = exp(2x)
#define EKTS 132                          // ekT k-stride (f32 words)

// workspace layout (bytes); total = 22,806,528
#define OFF_KEYS_BF   0u          // 16384x512 bf16
#define OFF_WK_BF     16777216u   // 512x512 bf16
#define OFF_EQB       17301504u   // 128x512 f32: exp2(S*q_part)
#define OFF_EPART     17563648u   // 4 x [8*2048*16] f32 partial logits
#define OFF_SC        21757952u   // 8x2048x16 f32 scores

// ---------------- K1: f32 -> bf16 conversion (keys + Wk only) -------------
__global__ __launch_bounds__(256) void k_convert(
    const float* __restrict__ keys, const float* __restrict__ W,
    unsigned short* __restrict__ keys_bf, unsigned short* __restrict__ wk_bf)
{
  int idx = (blockIdx.x * 256 + threadIdx.x) * 8;
  const float* src;
  unsigned short* dst;
  if (idx < KEYS_N) { src = keys + idx; dst = keys_bf + idx; }
  else {
    int e = idx - KEYS_N;                    // wk[h][c], h=e>>9, c=e&511
    src = W + (size_t)(e >> 9) * 1024 + 512 + (e & 511);
    dst = wk_bf + e;
  }
  float4 a = *(const float4*)src;
  float4 b = *(const float4*)(src + 4);
  ushort8 o;
  o[0]=f2bf(a.x); o[1]=f2bf(a.y); o[2]=f2bf(a.z); o[3]=f2bf(a.w);
  o[4]=f2bf(b.x); o[5]=f2bf(b.y); o[6]=f2bf(b.z); o[7]=f2bf(b.w);
  *(ushort8*)dst = o;
}

// ---------------- K2: q-GEMM (reg-staged f32): eqb = exp2(S*query·Wq^T) ---
__global__ __launch_bounds__(256) void k_qgemm(
    const float* __restrict__ query, const float* __restrict__ W,
    float* __restrict__ eqb)
{
  __shared__ struct { short A[128*32]; short B[128*32]; } g;
  const int tid = threadIdx.x;
  const int l = tid & 63, w = tid >> 6;
  const int n0 = blockIdx.x * 128;

  f32x4 acc[4][4];
  #pragma unroll
  for (int i = 0; i < 4; ++i)
    #pragma unroll
    for (int j = 0; j < 4; ++j) acc[i][j] = (f32x4){0.f,0.f,0.f,0.f};

  float4 areg[4], breg[4];
  auto gload = [&](int kt) {
    const int k0 = kt * 32;
    #pragma unroll
    for (int m = 0; m < 4; ++m) {
      const int f = tid * 4 + m * 1024;
      const int row = f >> 5, col = f & 31;
      areg[m] = *(const float4*)(query + (size_t)row * 512 + k0 + col);
      breg[m] = *(const float4*)(W + (size_t)(n0 + row) * 1024 + k0 + col);
    }
  };
  auto dswrite = [&]() {
    #pragma unroll
    for (int m = 0; m < 4; ++m) {
      const int f = tid * 4 + m * 1024;
      const int row = f >> 5, col = f & 31;
      const int o = row * 32 + (((col >> 3) ^ ((row >> 1) & 3)) << 3) + (col & 7);
      *(uint2*)&g.A[o] = make_uint2(pk2(areg[m].x, areg[m].y), pk2(areg[m].z, areg[m].w));
      *(uint2*)&g.B[o] = make_uint2(pk2(breg[m].x, breg[m].y), pk2(breg[m].z, breg[m].w));
    }
  };
  const int wm = w >> 1, wn = w & 1;
  const int fr = l & 15, fg = l >> 4;
  auto compute = [&]() {
    bf16x8 af[4], bfv[4];
    #pragma unroll
    for (int i = 0; i < 4; ++i) {
      const int ar = wm*64 + i*16 + fr;
      af[i]  = *(const bf16x8*)&g.A[ar*32 + ((fg ^ ((ar>>1)&3)) << 3)];
      const int br = wn*64 + i*16 + fr;
      bfv[i] = *(const bf16x8*)&g.B[br*32 + ((fg ^ ((br>>1)&3)) << 3)];
    }
    #pragma unroll
    for (int i = 0; i < 4; ++i)
      #pragma unroll
      for (int j = 0; j < 4; ++j)
        acc[i][j] = __builtin_amdgcn_mfma_f32_16x16x32_bf16(af[i], bfv[j], acc[i][j], 0, 0, 0);
  };

  gload(0);
  dswrite();
  for (int kt = 0; kt < 16; ++kt) {
    __syncthreads();
    if (kt < 15) gload(kt + 1);
    compute();
    __syncthreads();
    if (kt < 15) dswrite();
  }
  #pragma unroll
  for (int j = 0; j < 4; ++j) {
    const int gh = n0 + wn*64 + j*16 + fr;
    #pragma unroll
    for (int i = 0; i < 4; ++i)
      #pragma unroll
      for (int r = 0; r < 4; ++r) {
        const int gm = wm*64 + i*16 + fg*4 + r;
        eqb[gm * 512 + gh] = exp2_f(acc[i][j][r] * SCALE_2LOG2E);
      }
  }
}

// ---------------- K3: FUSED k-GEMM + energy (gload_lds BK=64 dbuf) --------
// ek stored TRANSPOSED ekT[h][k] stride 132: writes are per-lane float4 over
// consecutive k (conflict-free min); reads scalar b32, 2-way alias (free).
struct FusedSM {
  union {
    struct { short A[2][8192]; short B[2][8192]; } g;   // 64 KB
    float ekT[128 * EKTS];                              // 66 KB
  } u;
  float eqs[16 * 128];                                  // 8 KB
};

__global__ __launch_bounds__(256, 2) void k_fused(
    const unsigned short* __restrict__ keys_bf, const unsigned short* __restrict__ wk_bf,
    const float* __restrict__ w_bias, const float* __restrict__ eqb,
    const float* __restrict__ vw, float* __restrict__ e_part)
{
  __shared__ FusedSM sm;
  const int tid = threadIdx.x;
  const int l = tid & 63, w = tid >> 6;
  const int by = blockIdx.x;              // 0..127 m-tile (128 k-rows)
  const int hc = blockIdx.y;              // 0..3 h-chunk
  const int h0 = hc * 128;
  const int b  = by >> 4;

  // stage eqs [16 q][128 h] early (disjoint LDS region; overlaps GEMM)
  {
    const int q = tid >> 4, c0 = (tid & 15) * 8;
    const float* src = eqb + (size_t)(b * 16 + q) * 512 + h0 + c0;
    *(float4*)&sm.eqs[q * 128 + c0]     = *(const float4*)src;
    *(float4*)&sm.eqs[q * 128 + c0 + 4] = *(const float4*)(src + 4);
  }
  // v weights (pre-scaled by -2); lane owns h-cols {s*32+g*4+u, s*32+16+g*4+u}
  const int g = l & 3, kl = l >> 2;
  float vv[32];
  #pragma unroll
  for (int s = 0; s < 4; ++s) {
    const float4 a0 = *(const float4*)(vw + h0 + s*32 + g*4);
    const float4 a1 = *(const float4*)(vw + h0 + s*32 + 16 + g*4);
    vv[s*8+0]=-2.f*a0.x; vv[s*8+1]=-2.f*a0.y; vv[s*8+2]=-2.f*a0.z; vv[s*8+3]=-2.f*a0.w;
    vv[s*8+4]=-2.f*a1.x; vv[s*8+5]=-2.f*a1.y; vv[s*8+6]=-2.f*a1.z; vv[s*8+7]=-2.f*a1.w;
  }

  const unsigned short* Aptr = keys_bf + (size_t)by * 128 * 512;
  const unsigned short* Bptr = wk_bf + (size_t)h0 * 512;

  const int srow = w * 32 + (l >> 3);          // staging row (r adds 8)
  const int scol = ((l & 7) ^ (l >> 3)) * 8;   // pre-swizzled global 16B chunk

  f32x4 acc[4][4];
  #pragma unroll
  for (int i = 0; i < 4; ++i)
    #pragma unroll
    for (int j = 0; j < 4; ++j) acc[i][j] = (f32x4){0.f,0.f,0.f,0.f};

  auto stage = [&](int buf, int kt) {
    const int k0 = kt * 64;
    #pragma unroll
    for (int r = 0; r < 4; ++r) {
      GLL16(Aptr + (srow + r * 8) * 512 + k0 + scol, &sm.u.g.A[buf][w * 2048 + r * 512]);
      GLL16(Bptr + (srow + r * 8) * 512 + k0 + scol, &sm.u.g.B[buf][w * 2048 + r * 512]);
    }
  };
  const int wm = w >> 1, wn = w & 1;
  const int fr = l & 15, fg = l >> 4;
  const int axk = fr & 7;                      // read-side XOR key
  auto compute = [&](int buf) {
    #pragma unroll
    for (int ks = 0; ks < 2; ++ks) {
      bf16x8 af[4], bfv[4];
      #pragma unroll
      for (int i = 0; i < 4; ++i) {
        af[i]  = *(const bf16x8*)&sm.u.g.A[buf][(wm*64 + i*16 + fr) * 64 + ((ks*4 + fg) ^ axk) * 8];
        bfv[i] = *(const bf16x8*)&sm.u.g.B[buf][(wn*64 + i*16 + fr) * 64 + ((ks*4 + fg) ^ axk) * 8];
      }
      #pragma unroll
      for (int i = 0; i < 4; ++i)
        #pragma unroll
        for (int j = 0; j < 4; ++j)
          acc[i][j] = __builtin_amdgcn_mfma_f32_16x16x32_bf16(af[i], bfv[j], acc[i][j], 0, 0, 0);
    }
  };
  stage(0, 0);
  for (int kt = 0; kt < 8; ++kt) {
    __syncthreads();
    if (kt < 7) stage((kt + 1) & 1, kt + 1);
    compute(kt & 1);
  }
  __syncthreads();                         // staging reads done before overwrite

  // ekT[h][k]: lane's 4 r-values are consecutive k -> one float4 per (i,j)
  #pragma unroll
  for (int j = 0; j < 4; ++j) {
    const int ch = wn*64 + j*16 + fr;      // local h col
    const float bias = w_bias[h0 + ch];
    #pragma unroll
    for (int i = 0; i < 4; ++i) {
      f32x4 ev;
      #pragma unroll
      for (int r = 0; r < 4; ++r)
        ev[r] = exp2_f((acc[i][j][r] + bias) * SCALE_2LOG2E);
      *(f32x4*)&sm.u.ekT[ch * EKTS + wm*64 + i*16 + fg*4] = ev;
    }
  }
  __syncthreads();

  // energy: wave w rows w*32..+31 in 2 passes; e' = sum_h vv_h/(1+ek*eq)
  #pragma unroll
  for (int p = 0; p < 2; ++p) {
    const int lr = w * 32 + p * 16 + kl;          // local k-row
    float ek[32];
    #pragma unroll
    for (int s = 0; s < 4; ++s)
      #pragma unroll
      for (int u = 0; u < 4; ++u) {
        ek[s*8+u]     = sm.u.ekT[(s*32 + g*4 + u) * EKTS + lr];
        ek[s*8+4+u]   = sm.u.ekT[(s*32 + 16 + g*4 + u) * EKTS + lr];
      }
    const size_t epbase = (size_t)hc * 262144 + ((size_t)(by * 128 + lr)) * 16;
    #pragma unroll 2
    for (int q = 0; q < 16; ++q) {
      float a0 = 0.f, a1 = 0.f;
      #pragma unroll
      for (int s = 0; s < 4; ++s) {
        const float* er = &sm.eqs[q * 128 + s * 32 + g * 4];
        const float4 E0 = *(const float4*)er;
        const float4 E1 = *(const float4*)(er + 16);
        a0 = fmaf(vv[s*8+0], rcp_f(fmaf(ek[s*8+0], E0.x, 1.f)), a0);
        a1 = fmaf(vv[s*8+1], rcp_f(fmaf(ek[s*8+1], E0.y, 1.f)), a1);
        a0 = fmaf(vv[s*8+2], rcp_f(fmaf(ek[s*8+2], E0.z, 1.f)), a0);
        a1 = fmaf(vv[s*8+3], rcp_f(fmaf(ek[s*8+3], E0.w, 1.f)), a1);
        a0 = fmaf(vv[s*8+4], rcp_f(fmaf(ek[s*8+4], E1.x, 1.f)), a0);
        a1 = fmaf(vv[s*8+5], rcp_f(fmaf(ek[s*8+5], E1.y, 1.f)), a1);
        a0 = fmaf(vv[s*8+6], rcp_f(fmaf(ek[s*8+6], E1.z, 1.f)), a0);
        a1 = fmaf(vv[s*8+7], rcp_f(fmaf(ek[s*8+7], E1.w, 1.f)), a1);
      }
      float a = a0 + a1;
      a += __shfl_xor(a, 1, 64);
      a += __shfl_xor(a, 2, 64);
      if (g == 0) e_part[epbase + q] = a;
    }
  }
}

// ---------------- K4: softmax over k: sum 4 partials, normalize -----------
__global__ __launch_bounds__(256) void k_softmax(
    const float* __restrict__ e_part, float* __restrict__ sc)
{
  const int b = blockIdx.x >> 4, q = blockIdx.x & 15;
  const int base = b * 32768 + q;           // stride 16 over k
  const int tid = threadIdx.x;
  __shared__ float redm[4], reds[4];

  float vals[8];
  float mx = -1e30f;
  #pragma unroll
  for (int i = 0; i < 8; ++i) {
    const int x = base + (tid + i * 256) * 16;
    vals[i] = (e_part[x] + e_part[x + 262144]) + (e_part[x + 524288] + e_part[x + 786432]);
    mx = fmaxf(mx, vals[i]);
  }
  #pragma unroll
  for (int msk = 1; msk < 64; msk <<= 1) mx = fmaxf(mx, __shfl_xor(mx, msk, 64));
  if ((tid & 63) == 0) redm[tid >> 6] = mx;
  __syncthreads();
  mx = fmaxf(fmaxf(redm[0], redm[1]), fmaxf(redm[2], redm[3]));

  float ex[8], sum = 0.f;
  #pragma unroll
  for (int i = 0; i < 8; ++i) { ex[i] = __expf(vals[i] - mx); sum += ex[i]; }
  #pragma unroll
  for (int msk = 1; msk < 64; msk <<= 1) sum += __shfl_xor(sum, msk, 64);
  if ((tid & 63) == 0) reds[tid >> 6] = sum;
  __syncthreads();
  sum = reds[0] + reds[1] + reds[2] + reds[3];
  const float r = 1.f / sum;
  #pragma unroll
  for (int i = 0; i < 8; ++i) sc[base + (tid + i * 256) * 16] = ex[i] * r;
}

// ---------------- K5: single-pass PV -> out ------------------------------
// block (b, nc): 32 n-cols, all 2048 k. thread (kg 0..7, n 0..31):
// acc[16 q] over its 256-k slice; kg-reduce via LDS; writes d_out directly.
__global__ __launch_bounds__(256) void k_pv(
    const float* __restrict__ values, const float* __restrict__ sc,
    float* __restrict__ out)
{
  __shared__ float s_sc[4096];               // 16 KB (chunk stage / kg-reduce)
  const int tid = threadIdx.x;
  const int nc = blockIdx.x & 15, b = blockIdx.x >> 4;
  const int n = tid & 31, kg = tid >> 5;
  const int n0 = nc * 32;

  float acc[16];
  #pragma unroll
  for (int q = 0; q < 16; ++q) acc[q] = 0.f;

  for (int kc = 0; kc < 16; ++kc) {
    __syncthreads();
    const float* ssrc = sc + (size_t)(b * 2048 + kc * 128) * 16;
    *(float4*)&s_sc[tid * 8]     = *(const float4*)&ssrc[tid * 8];
    *(float4*)&s_sc[tid * 8 + 4] = *(const float4*)&ssrc[tid * 8 + 4];
    __syncthreads();
    const float* vb = values + ((size_t)(b * 2048 + kc * 128 + kg * 16)) * 512 + n0 + n;
    #pragma unroll
    for (int k2 = 0; k2 < 16; ++k2) {
      const float v = vb[(size_t)k2 * 512];
      const float* sr = &s_sc[(kg * 16 + k2) * 16];
      #pragma unroll
      for (int qq = 0; qq < 4; ++qq) {
        const float4 s4 = *(const float4*)&sr[qq * 4];
        acc[qq*4+0] = fmaf(v, s4.x, acc[qq*4+0]);
        acc[qq*4+1] = fmaf(v, s4.y, acc[qq*4+1]);
        acc[qq*4+2] = fmaf(v, s4.z, acc[qq*4+2]);
        acc[qq*4+3] = fmaf(v, s4.w, acc[qq*4+3]);
      }
    }
  }
  __syncthreads();
  #pragma unroll
  for (int q = 0; q < 16; ++q) s_sc[(kg * 16 + q) * 32 + n] = acc[q];
  __syncthreads();
  #pragma unroll
  for (int t = 0; t < 2; ++t) {
    const int idx = tid + t * 256;           // q*32+n'
    const int q = idx >> 5, nn = idx & 31;
    float s = 0.f;
    #pragma unroll
    for (int k2 = 0; k2 < 8; ++k2) s += s_sc[(k2 * 16 + q) * 32 + nn];
    out[((size_t)(b * 16 + q)) * 512 + n0 + nn] = s;
  }
}

extern "C" void kernel_launch(void* const* d_in, const int* in_sizes, int n_in,
                              void* d_out, int out_size, void* d_ws, size_t ws_size,
                              hipStream_t stream)
{
  const float* query  = (const float*)d_in[0];
  const float* keys   = (const float*)d_in[1];
  const float* values = (const float*)d_in[2];
  const float* W      = (const float*)d_in[3];
  const float* w_bias = (const float*)d_in[4];
  const float* vw     = (const float*)d_in[5];
  // d_in[6] (v_bias) + sum_h v_h are (k)-constant logit shifts -> softmax-invariant.

  char* ws = (char*)d_ws;
  unsigned short* keys_bf = (unsigned short*)(ws + OFF_KEYS_BF);
  unsigned short* wk_bf   = (unsigned short*)(ws + OFF_WK_BF);
  float* eqb    = (float*)(ws + OFF_EQB);
  float* e_part = (float*)(ws + OFF_EPART);
  float* sc     = (float*)(ws + OFF_SC);

  hipLaunchKernelGGL(k_convert, dim3(4224), dim3(256), 0, stream,
                     keys, W, keys_bf, wk_bf);
  hipLaunchKernelGGL(k_qgemm, dim3(4), dim3(256), 0, stream, query, W, eqb);
  hipLaunchKernelGGL(k_fused, dim3(128, 4), dim3(256), 0, stream,
                     keys_bf, wk_bf, w_bias, eqb, vw, e_part);
  hipLaunchKernelGGL(k_softmax, dim3(128), dim3(256), 0, stream, e_part, sc);
  hipLaunchKernelGGL(k_pv, dim3(128), dim3(256), 0, stream, values, sc, (float*)d_out);
}

// Round 8
// 104.058 us; speedup vs baseline: 1.0544x; 1.0050x over previous
//
#include <hip/hip_runtime.h>
#include <cstddef>

using bf16x8  = __attribute__((ext_vector_type(8))) short;
using short4v = __attribute__((ext_vector_type(4))) short;
using f32x4   = __attribute__((ext_vector_type(4))) float;
using ushort8 = __attribute__((ext_vector_type(8))) unsigned short;

#define GLL16(gp, lp) __builtin_amdgcn_global_load_lds( \
    (const __attribute__((address_space(1))) unsigned int*)(const void*)(gp), \
    (__attribute__((address_space(3))) unsigned int*)(void*)(lp), 16, 0, 0)

__device__ __forceinline__ float exp2_f(float x){ float r; asm("v_exp_f32 %0, %1" : "=v"(r) : "v"(x)); return r; }
__device__ __forceinline__ float rcp_f (float x){ float r; asm("v_rcp_f32 %0, %1" : "=v"(r) : "v"(x)); return r; }
__device__ __forceinline__ unsigned short f2bf(float f){
  unsigned int u = __float_as_uint(f);
  u = u + 0x7FFFu + ((u >> 16) & 1u);
  return (unsigned short)(u >> 16);
}
__device__ __forceinline__ float bf2f(unsigned short s){
  return __uint_as_float(((unsigned int)s) << 16);
}

// problem sizes: B=8 Q=16 KV=2048 NQ=NK=NV=H=512
#define KEYS_N   8388608
#define SCALE_2LOG2E 2.885390081777927f   // 2*log2(e): exp2(x*S) = exp(2x)

// workspace layout (bytes); total = 22,806,528
#define OFF_KEYS_BF   0u          // 16384x512 bf16
#define OFF_WK_BF     16777216u   // 512x512 bf16
#define OFF_EQB       17301504u   // 128x512 f32: exp2(S*q_part)
#define OFF_EPART     17563648u   // 4 x [8*2048*16] f32 partial logits
#define OFF_SC        21757952u   // 8x2048x16 f32 scores

// ---------------- K1: f32 -> bf16 conversion (keys + Wk) ------------------
__global__ __launch_bounds__(256) void k_convert(
    const float* __restrict__ keys, const float* __restrict__ W,
    unsigned short* __restrict__ keys_bf, unsigned short* __restrict__ wk_bf)
{
  int idx = (blockIdx.x * 256 + threadIdx.x) * 8;
  const float* src;
  unsigned short* dst;
  if (idx < KEYS_N) { src = keys + idx; dst = keys_bf + idx; }
  else {
    int e = idx - KEYS_N;                    // wk[h][c], h=e>>9, c=e&511
    src = W + (size_t)(e >> 9) * 1024 + 512 + (e & 511);
    dst = wk_bf + e;
  }
  float4 a = *(const float4*)src;
  float4 b = *(const float4*)(src + 4);
  ushort8 o;
  o[0]=f2bf(a.x); o[1]=f2bf(a.y); o[2]=f2bf(a.z); o[3]=f2bf(a.w);
  o[4]=f2bf(b.x); o[5]=f2bf(b.y); o[6]=f2bf(b.z); o[7]=f2bf(b.w);
  *(ushort8*)dst = o;
}

// q/Wq bf16 convert: qw_bf rows 0..127 = query, rows 128..639 = Wq ---------
// 160 blocks x 2048 elems = 327,680 exact.
__global__ __launch_bounds__(256) void k_convq(
    const float* __restrict__ query, const float* __restrict__ W,
    unsigned short* __restrict__ qw_bf)
{
  int idx = (blockIdx.x * 256 + threadIdx.x) * 8;
  const float* src;
  if (idx < 65536) src = query + idx;
  else { int e = idx - 65536; src = W + (size_t)(e >> 9) * 1024 + (e & 511); }
  float4 a = *(const float4*)src;
  float4 b = *(const float4*)(src + 4);
  ushort8 o;
  o[0]=f2bf(a.x); o[1]=f2bf(a.y); o[2]=f2bf(a.z); o[3]=f2bf(a.w);
  o[4]=f2bf(b.x); o[5]=f2bf(b.y); o[6]=f2bf(b.z); o[7]=f2bf(b.w);
  *(ushort8*)&qw_bf[idx] = o;
}

// ---------------- K2: q-GEMM: eqb = exp2(S*query·Wq^T), 16 blocks ---------
// tile M=128, N=32, K=512; 4 waves 64m x 16n; GLL16 staging, BK=64 single-buf.
__global__ __launch_bounds__(256) void k_qgemm(
    const unsigned short* __restrict__ query_bf, float* __restrict__ eqb)
{
  __shared__ struct { short A[128*64]; short B[32*64]; } g;
  const int tid = threadIdx.x;
  const int l = tid & 63, w = tid >> 6;
  const int n0 = blockIdx.x * 32;
  const int wm = w & 1, wn = w >> 1;
  const int fr = l & 15, fg = l >> 4;
  const int axk = fr & 7;

  f32x4 acc[4];
  #pragma unroll
  for (int i = 0; i < 4; ++i) acc[i] = (f32x4){0.f,0.f,0.f,0.f};

  const int srow8 = (l >> 3);                 // row within 8-row group
  const int schk  = ((l & 7) ^ srow8) * 8;    // swizzled source chunk

  for (int kt = 0; kt < 8; ++kt) {
    const int k0 = kt * 64;
    #pragma unroll
    for (int r = 0; r < 4; ++r)
      GLL16(query_bf + (size_t)(r * 32 + w * 8 + srow8) * 512 + k0 + schk,
            &g.A[r * 2048 + w * 512]);
    GLL16(query_bf + (size_t)(128 + n0 + w * 8 + srow8) * 512 + k0 + schk,
          &g.B[w * 512]);
    __syncthreads();
    #pragma unroll
    for (int ks = 0; ks < 2; ++ks) {
      bf16x8 af[4], bfv;
      #pragma unroll
      for (int i = 0; i < 4; ++i)
        af[i] = *(const bf16x8*)&g.A[(wm*64 + i*16 + fr) * 64 + ((ks*4 + fg) ^ axk) * 8];
      bfv = *(const bf16x8*)&g.B[(wn*16 + fr) * 64 + ((ks*4 + fg) ^ axk) * 8];
      #pragma unroll
      for (int i = 0; i < 4; ++i)
        acc[i] = __builtin_amdgcn_mfma_f32_16x16x32_bf16(af[i], bfv, acc[i], 0, 0, 0);
    }
    __syncthreads();
  }
  const int gh = n0 + wn*16 + fr;
  #pragma unroll
  for (int i = 0; i < 4; ++i)
    #pragma unroll
    for (int r = 0; r < 4; ++r) {
      const int gm = wm*64 + i*16 + fg*4 + r;
      eqb[gm * 512 + gh] = exp2_f(acc[i][r] * SCALE_2LOG2E);
    }
}

// ---------------- K3: FUSED k-GEMM + energy, 4 blocks/CU ------------------
// LDS 40KB: union{staging A+B 32KB, ekbf[128][128] bf16 32KB} + eqs 8KB.
// ekbf 16B-chunk XOR swizzle: chunk' = chunk ^ (row&15). All waves write acc
// (acc dies), then 2 energy passes: e' = sum_h vv_h / (1 + ek*eq).
struct FusedSM {
  union {
    struct { short A[8192]; short B[8192]; } g;   // 32 KB single-buffer BK=64
    unsigned short ekbf[128 * 128];               // 32 KB
  } u;
  float eqs[16 * 128];                            // 8 KB
};

__global__ __launch_bounds__(256, 4) void k_fused(
    const unsigned short* __restrict__ keys_bf, const unsigned short* __restrict__ wk_bf,
    const float* __restrict__ w_bias, const float* __restrict__ eqb,
    const float* __restrict__ vw, float* __restrict__ e_part)
{
  __shared__ FusedSM sm;
  const int tid = threadIdx.x;
  const int l = tid & 63, w = tid >> 6;
  const int by = blockIdx.x;              // 0..127 m-tile (128 k-rows)
  const int hc = blockIdx.y;              // 0..3 h-chunk
  const int h0 = hc * 128;
  const int b  = by >> 4;

  // stage eqs [16 q][128 h] (disjoint LDS region)
  {
    const int q = tid >> 4, c0 = (tid & 15) * 8;
    const float* src = eqb + (size_t)(b * 16 + q) * 512 + h0 + c0;
    *(float4*)&sm.eqs[q * 128 + c0]     = *(const float4*)src;
    *(float4*)&sm.eqs[q * 128 + c0 + 4] = *(const float4*)(src + 4);
  }

  const unsigned short* Aptr = keys_bf + (size_t)by * 128 * 512;
  const unsigned short* Bptr = wk_bf + (size_t)h0 * 512;

  const int srow = w * 32 + (l >> 3);
  const int scol = ((l & 7) ^ (l >> 3)) * 8;
  const int wm = w >> 1, wn = w & 1;
  const int fr = l & 15, fg = l >> 4;
  const int axk = fr & 7;

  f32x4 acc[4][4];
  #pragma unroll
  for (int i = 0; i < 4; ++i)
    #pragma unroll
    for (int j = 0; j < 4; ++j) acc[i][j] = (f32x4){0.f,0.f,0.f,0.f};

  for (int kt = 0; kt < 8; ++kt) {
    const int k0 = kt * 64;
    #pragma unroll
    for (int r = 0; r < 4; ++r) {
      GLL16(Aptr + (srow + r * 8) * 512 + k0 + scol, &sm.u.g.A[w * 2048 + r * 512]);
      GLL16(Bptr + (srow + r * 8) * 512 + k0 + scol, &sm.u.g.B[w * 2048 + r * 512]);
    }
    __syncthreads();                       // loads landed
    #pragma unroll
    for (int ks = 0; ks < 2; ++ks) {
      bf16x8 af[4], bfv[4];
      #pragma unroll
      for (int i = 0; i < 4; ++i) {
        af[i]  = *(const bf16x8*)&sm.u.g.A[(wm*64 + i*16 + fr) * 64 + ((ks*4 + fg) ^ axk) * 8];
        bfv[i] = *(const bf16x8*)&sm.u.g.B[(wn*64 + i*16 + fr) * 64 + ((ks*4 + fg) ^ axk) * 8];
      }
      #pragma unroll
      for (int i = 0; i < 4; ++i)
        #pragma unroll
        for (int j = 0; j < 4; ++j)
          acc[i][j] = __builtin_amdgcn_mfma_f32_16x16x32_bf16(af[i], bfv[j], acc[i][j], 0, 0, 0);
    }
    __syncthreads();                       // reads done before next overwrite
  }

  // all waves: acc -> ekbf (bf16), swizzled chunk' = (col>>3) ^ (row&15)
  #pragma unroll
  for (int j = 0; j < 4; ++j) {
    const int col = wn*64 + j*16 + fr;
    const float bias = w_bias[h0 + col];
    const int chunk = col >> 3, coff = col & 7;
    #pragma unroll
    for (int i = 0; i < 4; ++i)
      #pragma unroll
      for (int r = 0; r < 4; ++r) {
        const int row = wm*64 + i*16 + fg*4 + r;       // row&15 = fg*4+r
        const float ev = exp2_f((acc[i][j][r] + bias) * SCALE_2LOG2E);
        sm.u.ekbf[row * 128 + ((chunk ^ (fg*4 + r)) << 3) + coff] = f2bf(ev);
      }
  }
  // v weights (pre-scaled by -2); lane owns h {s*32+g*4+u, s*32+16+g*4+u}
  const int g = l & 3, kl = l >> 2;
  float vv[32];
  #pragma unroll
  for (int s = 0; s < 4; ++s) {
    const float4 a0 = *(const float4*)(vw + h0 + s*32 + g*4);
    const float4 a1 = *(const float4*)(vw + h0 + s*32 + 16 + g*4);
    vv[s*8+0]=-2.f*a0.x; vv[s*8+1]=-2.f*a0.y; vv[s*8+2]=-2.f*a0.z; vv[s*8+3]=-2.f*a0.w;
    vv[s*8+4]=-2.f*a1.x; vv[s*8+5]=-2.f*a1.y; vv[s*8+6]=-2.f*a1.z; vv[s*8+7]=-2.f*a1.w;
  }
  __syncthreads();

  // energy: wave w rows w*32..+31 in 2 passes of 16; all 16 q per thread
  #pragma unroll
  for (int p = 0; p < 2; ++p) {
    const int lr = w * 32 + p * 16 + kl;          // lr&15 = kl
    float ek[32];
    #pragma unroll
    for (int s = 0; s < 4; ++s)
      #pragma unroll
      for (int hf = 0; hf < 2; ++hf) {
        const int ck = (4*s + 2*hf + (g >> 1)) ^ kl;
        const short4v v4 = *(const short4v*)&sm.u.ekbf[lr * 128 + (ck << 3) + (g & 1) * 4];
        ek[s*8 + hf*4 + 0] = bf2f((unsigned short)v4[0]);
        ek[s*8 + hf*4 + 1] = bf2f((unsigned short)v4[1]);
        ek[s*8 + hf*4 + 2] = bf2f((unsigned short)v4[2]);
        ek[s*8 + hf*4 + 3] = bf2f((unsigned short)v4[3]);
      }
    const size_t epbase = (size_t)hc * 262144 + ((size_t)(by * 128 + lr)) * 16;
    #pragma unroll 2
    for (int q = 0; q < 16; ++q) {
      float a0 = 0.f, a1 = 0.f;
      #pragma unroll
      for (int s = 0; s < 4; ++s) {
        const float* er = &sm.eqs[q * 128 + s * 32 + g * 4];
        const float4 E0 = *(const float4*)er;
        const float4 E1 = *(const float4*)(er + 16);
        a0 = fmaf(vv[s*8+0], rcp_f(fmaf(ek[s*8+0], E0.x, 1.f)), a0);
        a1 = fmaf(vv[s*8+1], rcp_f(fmaf(ek[s*8+1], E0.y, 1.f)), a1);
        a0 = fmaf(vv[s*8+2], rcp_f(fmaf(ek[s*8+2], E0.z, 1.f)), a0);
        a1 = fmaf(vv[s*8+3], rcp_f(fmaf(ek[s*8+3], E0.w, 1.f)), a1);
        a0 = fmaf(vv[s*8+4], rcp_f(fmaf(ek[s*8+4], E1.x, 1.f)), a0);
        a1 = fmaf(vv[s*8+5], rcp_f(fmaf(ek[s*8+5], E1.y, 1.f)), a1);
        a0 = fmaf(vv[s*8+6], rcp_f(fmaf(ek[s*8+6], E1.z, 1.f)), a0);
        a1 = fmaf(vv[s*8+7], rcp_f(fmaf(ek[s*8+7], E1.w, 1.f)), a1);
      }
      float a = a0 + a1;
      a += __shfl_xor(a, 1, 64);
      a += __shfl_xor(a, 2, 64);
      if (g == 0) e_part[epbase + q] = a;
    }
  }
}

// ---------------- K4: softmax over k: sum 4 partials, normalize -----------
__global__ __launch_bounds__(256) void k_softmax(
    const float* __restrict__ e_part, float* __restrict__ sc)
{
  const int b = blockIdx.x >> 4, q = blockIdx.x & 15;
  const int base = b * 32768 + q;           // stride 16 over k
  const int tid = threadIdx.x;
  __shared__ float redm[4], reds[4];

  float vals[8];
  float mx = -1e30f;
  #pragma unroll
  for (int i = 0; i < 8; ++i) {
    const int x = base + (tid + i * 256) * 16;
    vals[i] = (e_part[x] + e_part[x + 262144]) + (e_part[x + 524288] + e_part[x + 786432]);
    mx = fmaxf(mx, vals[i]);
  }
  #pragma unroll
  for (int msk = 1; msk < 64; msk <<= 1) mx = fmaxf(mx, __shfl_xor(mx, msk, 64));
  if ((tid & 63) == 0) redm[tid >> 6] = mx;
  __syncthreads();
  mx = fmaxf(fmaxf(redm[0], redm[1]), fmaxf(redm[2], redm[3]));

  float ex[8], sum = 0.f;
  #pragma unroll
  for (int i = 0; i < 8; ++i) { ex[i] = __expf(vals[i] - mx); sum += ex[i]; }
  #pragma unroll
  for (int msk = 1; msk < 64; msk <<= 1) sum += __shfl_xor(sum, msk, 64);
  if ((tid & 63) == 0) reds[tid >> 6] = sum;
  __syncthreads();
  sum = reds[0] + reds[1] + reds[2] + reds[3];
  const float r = 1.f / sum;
  #pragma unroll
  for (int i = 0; i < 8; ++i) sc[base + (tid + i * 256) * 16] = ex[i] * r;
}

// ---------------- K5: single-pass PV -> out, 256 blocks -------------------
// block (b, nc): 16 n-cols, all 2048 k. thread (kg 0..15, n 0..15):
// acc[16 q] over 128-k slice; kg-reduce: 2 shuffles + LDS; write d_out.
__global__ __launch_bounds__(256) void k_pv(
    const float* __restrict__ values, const float* __restrict__ sc,
    float* __restrict__ out)
{
  __shared__ float lds[2048];                // 8 KB
  const int tid = threadIdx.x;
  const int nc = blockIdx.x & 31, b = blockIdx.x >> 5;
  const int n = tid & 15, kg = tid >> 4;
  const int l = tid & 63, w = tid >> 6;
  const int n0 = nc * 16;

  float acc[16];
  #pragma unroll
  for (int q = 0; q < 16; ++q) acc[q] = 0.f;

  for (int kc = 0; kc < 16; ++kc) {
    __syncthreads();
    const float* ssrc = sc + (size_t)(b * 2048 + kc * 128) * 16;
    *(float4*)&lds[tid * 8]     = *(const float4*)&ssrc[tid * 8];
    *(float4*)&lds[tid * 8 + 4] = *(const float4*)&ssrc[tid * 8 + 4];
    __syncthreads();
    const float* vb = values + ((size_t)(b * 2048 + kc * 128 + kg * 8)) * 512 + n0 + n;
    #pragma unroll
    for (int k2 = 0; k2 < 8; ++k2) {
      const float v = vb[(size_t)k2 * 512];
      const float* sr = &lds[(kg * 8 + k2) * 16];
      #pragma unroll
      for (int qq = 0; qq < 4; ++qq) {
        const float4 s4 = *(const float4*)&sr[qq * 4];
        acc[qq*4+0] = fmaf(v, s4.x, acc[qq*4+0]);
        acc[qq*4+1] = fmaf(v, s4.y, acc[qq*4+1]);
        acc[qq*4+2] = fmaf(v, s4.z, acc[qq*4+2]);
        acc[qq*4+3] = fmaf(v, s4.w, acc[qq*4+3]);
      }
    }
  }
  // reduce kg within wave (4 kg-groups per wave): lanes l, l^16, l^32 share n
  #pragma unroll
  for (int q = 0; q < 16; ++q) {
    acc[q] += __shfl_xor(acc[q], 16, 64);
    acc[q] += __shfl_xor(acc[q], 32, 64);
  }
  __syncthreads();
  if (l < 16) {
    #pragma unroll
    for (int q = 0; q < 16; ++q) lds[w * 256 + q * 16 + l] = acc[q];
  }
  __syncthreads();
  const int q = tid >> 4, nn = tid & 15;
  const float s = (lds[q * 16 + nn] + lds[256 + q * 16 + nn]) +
                  (lds[512 + q * 16 + nn] + lds[768 + q * 16 + nn]);
  out[((size_t)(b * 16 + q)) * 512 + n0 + nn] = s;
}

extern "C" void kernel_launch(void* const* d_in, const int* in_sizes, int n_in,
                              void* d_out, int out_size, void* d_ws, size_t ws_size,
                              hipStream_t stream)
{
  const float* query  = (const float*)d_in[0];
  const float* keys   = (const float*)d_in[1];
  const float* values = (const float*)d_in[2];
  const float* W      = (const float*)d_in[3];
  const float* w_bias = (const float*)d_in[4];
  const float* vw     = (const float*)d_in[5];
  // d_in[6] (v_bias) + sum_h v_h are (k)-constant logit shifts -> softmax-invariant.

  char* ws = (char*)d_ws;
  unsigned short* keys_bf = (unsigned short*)(ws + OFF_KEYS_BF);
  unsigned short* wk_bf   = (unsigned short*)(ws + OFF_WK_BF);
  float* eqb    = (float*)(ws + OFF_EQB);
  float* e_part = (float*)(ws + OFF_EPART);
  float* sc     = (float*)(ws + OFF_SC);
  // qw_bf (query 128 rows + Wq 512 rows, 512 cols bf16 = 640KB) aliases the
  // e_part region (4MB); qw_bf is dead before k_fused writes e_part.
  unsigned short* qw_bf = (unsigned short*)(ws + OFF_EPART);

  hipLaunchKernelGGL(k_convq, dim3(160), dim3(256), 0, stream, query, W, qw_bf);
  hipLaunchKernelGGL(k_convert, dim3(4224), dim3(256), 0, stream,
                     keys, W, keys_bf, wk_bf);
  hipLaunchKernelGGL(k_qgemm, dim3(16), dim3(256), 0, stream, qw_bf, eqb);
  hipLaunchKernelGGL(k_fused, dim3(128, 4), dim3(256), 0, stream,
                     keys_bf, wk_bf, w_bias, eqb, vw, e_part);
  hipLaunchKernelGGL(k_softmax, dim3(128), dim3(256), 0, stream, e_part, sc);
  hipLaunchKernelGGL(k_pv, dim3(256), dim3(256), 0, stream, values, sc, (float*)d_out);
}

// Round 9
// 93.970 us; speedup vs baseline: 1.1676x; 1.1073x over previous
//
#include <hip/hip_runtime.h>
#include <cstddef>

using bf16x8  = __attribute__((ext_vector_type(8))) short;
using short4v = __attribute__((ext_vector_type(4))) short;
using f32x4   = __attribute__((ext_vector_type(4))) float;
using ushort8 = __attribute__((ext_vector_type(8))) unsigned short;

#define GLL16(gp, lp) __builtin_amdgcn_global_load_lds( \
    (const __attribute__((address_space(1))) unsigned int*)(const void*)(gp), \
    (__attribute__((address_space(3))) unsigned int*)(void*)(lp), 16, 0, 0)

__device__ __forceinline__ float exp2_f(float x){ float r; asm("v_exp_f32 %0, %1" : "=v"(r) : "v"(x)); return r; }
__device__ __forceinline__ float rcp_f (float x){ float r; asm("v_rcp_f32 %0, %1" : "=v"(r) : "v"(x)); return r; }
__device__ __forceinline__ unsigned short f2bf(float f){
  unsigned int u = __float_as_uint(f);
  u = u + 0x7FFFu + ((u >> 16) & 1u);
  return (unsigned short)(u >> 16);
}
__device__ __forceinline__ float bf2f(unsigned short s){
  return __uint_as_float(((unsigned int)s) << 16);
}

// problem sizes: B=8 Q=16 KV=2048 NQ=NK=NV=H=512
#define KEYS_N   8388608
#define SCALE_2LOG2E 2.885390081777927f   // 2*log2(e): exp2(x*S) = exp(2x)

// workspace layout (bytes); total = 22,806,528
#define OFF_KEYS_BF   0u          // 16384x512 bf16
#define OFF_WK_BF     16777216u   // 512x512 bf16
#define OFF_EQB       17301504u   // 128x512 f32: exp2(S*q_part)
#define OFF_EPART     17563648u   // 4 x [8*2048*16] f32 partial logits
#define OFF_SC        21757952u   // 8x2048x16 f32 scores

// ---------------- K1: f32 -> bf16 conversion (keys + Wk) ------------------
__global__ __launch_bounds__(256) void k_convert(
    const float* __restrict__ keys, const float* __restrict__ W,
    unsigned short* __restrict__ keys_bf, unsigned short* __restrict__ wk_bf)
{
  int idx = (blockIdx.x * 256 + threadIdx.x) * 8;
  const float* src;
  unsigned short* dst;
  if (idx < KEYS_N) { src = keys + idx; dst = keys_bf + idx; }
  else {
    int e = idx - KEYS_N;                    // wk[h][c], h=e>>9, c=e&511
    src = W + (size_t)(e >> 9) * 1024 + 512 + (e & 511);
    dst = wk_bf + e;
  }
  float4 a = *(const float4*)src;
  float4 b = *(const float4*)(src + 4);
  ushort8 o;
  o[0]=f2bf(a.x); o[1]=f2bf(a.y); o[2]=f2bf(a.z); o[3]=f2bf(a.w);
  o[4]=f2bf(b.x); o[5]=f2bf(b.y); o[6]=f2bf(b.z); o[7]=f2bf(b.w);
  *(ushort8*)dst = o;
}

// q/Wq bf16 convert: qw_bf rows 0..127 = query, rows 128..639 = Wq ---------
// 160 blocks x 2048 elems = 327,680 exact.
__global__ __launch_bounds__(256) void k_convq(
    const float* __restrict__ query, const float* __restrict__ W,
    unsigned short* __restrict__ qw_bf)
{
  int idx = (blockIdx.x * 256 + threadIdx.x) * 8;
  const float* src;
  if (idx < 65536) src = query + idx;
  else { int e = idx - 65536; src = W + (size_t)(e >> 9) * 1024 + (e & 511); }
  float4 a = *(const float4*)src;
  float4 b = *(const float4*)(src + 4);
  ushort8 o;
  o[0]=f2bf(a.x); o[1]=f2bf(a.y); o[2]=f2bf(a.z); o[3]=f2bf(a.w);
  o[4]=f2bf(b.x); o[5]=f2bf(b.y); o[6]=f2bf(b.z); o[7]=f2bf(b.w);
  *(ushort8*)&qw_bf[idx] = o;
}

// ---------------- K2: q-GEMM: eqb = exp2(S*query·Wq^T), 16 blocks ---------
// tile M=128, N=32, K=512; 4 waves 64m x 16n; GLL16 staging, BK=64 single-buf.
__global__ __launch_bounds__(256) void k_qgemm(
    const unsigned short* __restrict__ query_bf, float* __restrict__ eqb)
{
  __shared__ struct { short A[128*64]; short B[32*64]; } g;
  const int tid = threadIdx.x;
  const int l = tid & 63, w = tid >> 6;
  const int n0 = blockIdx.x * 32;
  const int wm = w & 1, wn = w >> 1;
  const int fr = l & 15, fg = l >> 4;
  const int axk = fr & 7;

  f32x4 acc[4];
  #pragma unroll
  for (int i = 0; i < 4; ++i) acc[i] = (f32x4){0.f,0.f,0.f,0.f};

  const int srow8 = (l >> 3);                 // row within 8-row group
  const int schk  = ((l & 7) ^ srow8) * 8;    // swizzled source chunk

  for (int kt = 0; kt < 8; ++kt) {
    const int k0 = kt * 64;
    #pragma unroll
    for (int r = 0; r < 4; ++r)
      GLL16(query_bf + (size_t)(r * 32 + w * 8 + srow8) * 512 + k0 + schk,
            &g.A[r * 2048 + w * 512]);
    GLL16(query_bf + (size_t)(128 + n0 + w * 8 + srow8) * 512 + k0 + schk,
          &g.B[w * 512]);
    __syncthreads();
    #pragma unroll
    for (int ks = 0; ks < 2; ++ks) {
      bf16x8 af[4], bfv;
      #pragma unroll
      for (int i = 0; i < 4; ++i)
        af[i] = *(const bf16x8*)&g.A[(wm*64 + i*16 + fr) * 64 + ((ks*4 + fg) ^ axk) * 8];
      bfv = *(const bf16x8*)&g.B[(wn*16 + fr) * 64 + ((ks*4 + fg) ^ axk) * 8];
      #pragma unroll
      for (int i = 0; i < 4; ++i)
        acc[i] = __builtin_amdgcn_mfma_f32_16x16x32_bf16(af[i], bfv, acc[i], 0, 0, 0);
    }
    __syncthreads();
  }
  const int gh = n0 + wn*16 + fr;
  #pragma unroll
  for (int i = 0; i < 4; ++i)
    #pragma unroll
    for (int r = 0; r < 4; ++r) {
      const int gm = wm*64 + i*16 + fg*4 + r;
      eqb[gm * 512 + gh] = exp2_f(acc[i][r] * SCALE_2LOG2E);
    }
}

// ---------------- K3: FUSED k-GEMM + energy, 3 blocks/CU ------------------
// LDS 40KB: union{staging A+B 32KB, ekbf[128][128] bf16 32KB} + eqs 8KB.
// launch_bounds(256,3): VGPR cap ~168 (kernel needs ~110-160; bound 4's cap
// of 128 caused the round-8 spill: VGPR=64 + 30MB scratch traffic).
struct FusedSM {
  union {
    struct { short A[8192]; short B[8192]; } g;   // 32 KB single-buffer BK=64
    unsigned short ekbf[128 * 128];               // 32 KB
  } u;
  float eqs[16 * 128];                            // 8 KB
};

__global__ __launch_bounds__(256, 3) void k_fused(
    const unsigned short* __restrict__ keys_bf, const unsigned short* __restrict__ wk_bf,
    const float* __restrict__ w_bias, const float* __restrict__ eqb,
    const float* __restrict__ vw, float* __restrict__ e_part)
{
  __shared__ FusedSM sm;
  const int tid = threadIdx.x;
  const int l = tid & 63, w = tid >> 6;
  const int by = blockIdx.x;              // 0..127 m-tile (128 k-rows)
  const int hc = blockIdx.y;              // 0..3 h-chunk
  const int h0 = hc * 128;
  const int b  = by >> 4;

  // stage eqs [16 q][128 h] (disjoint LDS region)
  {
    const int q = tid >> 4, c0 = (tid & 15) * 8;
    const float* src = eqb + (size_t)(b * 16 + q) * 512 + h0 + c0;
    *(float4*)&sm.eqs[q * 128 + c0]     = *(const float4*)src;
    *(float4*)&sm.eqs[q * 128 + c0 + 4] = *(const float4*)(src + 4);
  }

  const unsigned short* Aptr = keys_bf + (size_t)by * 128 * 512;
  const unsigned short* Bptr = wk_bf + (size_t)h0 * 512;

  const int srow = w * 32 + (l >> 3);
  const int scol = ((l & 7) ^ (l >> 3)) * 8;
  const int wm = w >> 1, wn = w & 1;
  const int fr = l & 15, fg = l >> 4;
  const int axk = fr & 7;

  f32x4 acc[4][4];
  #pragma unroll
  for (int i = 0; i < 4; ++i)
    #pragma unroll
    for (int j = 0; j < 4; ++j) acc[i][j] = (f32x4){0.f,0.f,0.f,0.f};

  for (int kt = 0; kt < 8; ++kt) {
    const int k0 = kt * 64;
    #pragma unroll
    for (int r = 0; r < 4; ++r) {
      GLL16(Aptr + (srow + r * 8) * 512 + k0 + scol, &sm.u.g.A[w * 2048 + r * 512]);
      GLL16(Bptr + (srow + r * 8) * 512 + k0 + scol, &sm.u.g.B[w * 2048 + r * 512]);
    }
    __syncthreads();                       // loads landed
    #pragma unroll
    for (int ks = 0; ks < 2; ++ks) {
      bf16x8 af[4], bfv[4];
      #pragma unroll
      for (int i = 0; i < 4; ++i) {
        af[i]  = *(const bf16x8*)&sm.u.g.A[(wm*64 + i*16 + fr) * 64 + ((ks*4 + fg) ^ axk) * 8];
        bfv[i] = *(const bf16x8*)&sm.u.g.B[(wn*64 + i*16 + fr) * 64 + ((ks*4 + fg) ^ axk) * 8];
      }
      #pragma unroll
      for (int i = 0; i < 4; ++i)
        #pragma unroll
        for (int j = 0; j < 4; ++j)
          acc[i][j] = __builtin_amdgcn_mfma_f32_16x16x32_bf16(af[i], bfv[j], acc[i][j], 0, 0, 0);
    }
    __syncthreads();                       // reads done before next overwrite
  }

  // all waves: acc -> ekbf (bf16), swizzled chunk' = (col>>3) ^ (row&15)
  #pragma unroll
  for (int j = 0; j < 4; ++j) {
    const int col = wn*64 + j*16 + fr;
    const float bias = w_bias[h0 + col];
    const int chunk = col >> 3, coff = col & 7;
    #pragma unroll
    for (int i = 0; i < 4; ++i)
      #pragma unroll
      for (int r = 0; r < 4; ++r) {
        const int row = wm*64 + i*16 + fg*4 + r;       // row&15 = fg*4+r
        const float ev = exp2_f((acc[i][j][r] + bias) * SCALE_2LOG2E);
        sm.u.ekbf[row * 128 + ((chunk ^ (fg*4 + r)) << 3) + coff] = f2bf(ev);
      }
  }
  // v weights (pre-scaled by -2); lane owns h {s*32+g*4+u, s*32+16+g*4+u}
  const int g = l & 3, kl = l >> 2;
  float vv[32];
  #pragma unroll
  for (int s = 0; s < 4; ++s) {
    const float4 a0 = *(const float4*)(vw + h0 + s*32 + g*4);
    const float4 a1 = *(const float4*)(vw + h0 + s*32 + 16 + g*4);
    vv[s*8+0]=-2.f*a0.x; vv[s*8+1]=-2.f*a0.y; vv[s*8+2]=-2.f*a0.z; vv[s*8+3]=-2.f*a0.w;
    vv[s*8+4]=-2.f*a1.x; vv[s*8+5]=-2.f*a1.y; vv[s*8+6]=-2.f*a1.z; vv[s*8+7]=-2.f*a1.w;
  }
  __syncthreads();

  // energy: wave w rows w*32..+31 in 2 passes of 16; all 16 q per thread
  #pragma unroll
  for (int p = 0; p < 2; ++p) {
    const int lr = w * 32 + p * 16 + kl;          // lr&15 = kl
    float ek[32];
    #pragma unroll
    for (int s = 0; s < 4; ++s)
      #pragma unroll
      for (int hf = 0; hf < 2; ++hf) {
        const int ck = (4*s + 2*hf + (g >> 1)) ^ kl;
        const short4v v4 = *(const short4v*)&sm.u.ekbf[lr * 128 + (ck << 3) + (g & 1) * 4];
        ek[s*8 + hf*4 + 0] = bf2f((unsigned short)v4[0]);
        ek[s*8 + hf*4 + 1] = bf2f((unsigned short)v4[1]);
        ek[s*8 + hf*4 + 2] = bf2f((unsigned short)v4[2]);
        ek[s*8 + hf*4 + 3] = bf2f((unsigned short)v4[3]);
      }
    const size_t epbase = (size_t)hc * 262144 + ((size_t)(by * 128 + lr)) * 16;
    #pragma unroll 2
    for (int q = 0; q < 16; ++q) {
      float a0 = 0.f, a1 = 0.f;
      #pragma unroll
      for (int s = 0; s < 4; ++s) {
        const float* er = &sm.eqs[q * 128 + s * 32 + g * 4];
        const float4 E0 = *(const float4*)er;
        const float4 E1 = *(const float4*)(er + 16);
        a0 = fmaf(vv[s*8+0], rcp_f(fmaf(ek[s*8+0], E0.x, 1.f)), a0);
        a1 = fmaf(vv[s*8+1], rcp_f(fmaf(ek[s*8+1], E0.y, 1.f)), a1);
        a0 = fmaf(vv[s*8+2], rcp_f(fmaf(ek[s*8+2], E0.z, 1.f)), a0);
        a1 = fmaf(vv[s*8+3], rcp_f(fmaf(ek[s*8+3], E0.w, 1.f)), a1);
        a0 = fmaf(vv[s*8+4], rcp_f(fmaf(ek[s*8+4], E1.x, 1.f)), a0);
        a1 = fmaf(vv[s*8+5], rcp_f(fmaf(ek[s*8+5], E1.y, 1.f)), a1);
        a0 = fmaf(vv[s*8+6], rcp_f(fmaf(ek[s*8+6], E1.z, 1.f)), a0);
        a1 = fmaf(vv[s*8+7], rcp_f(fmaf(ek[s*8+7], E1.w, 1.f)), a1);
      }
      float a = a0 + a1;
      a += __shfl_xor(a, 1, 64);
      a += __shfl_xor(a, 2, 64);
      if (g == 0) e_part[epbase + q] = a;
    }
  }
}

// ---------------- K4: softmax over k: sum 4 partials, normalize -----------
__global__ __launch_bounds__(256) void k_softmax(
    const float* __restrict__ e_part, float* __restrict__ sc)
{
  const int b = blockIdx.x >> 4, q = blockIdx.x & 15;
  const int base = b * 32768 + q;           // stride 16 over k
  const int tid = threadIdx.x;
  __shared__ float redm[4], reds[4];

  float vals[8];
  float mx = -1e30f;
  #pragma unroll
  for (int i = 0; i < 8; ++i) {
    const int x = base + (tid + i * 256) * 16;
    vals[i] = (e_part[x] + e_part[x + 262144]) + (e_part[x + 524288] + e_part[x + 786432]);
    mx = fmaxf(mx, vals[i]);
  }
  #pragma unroll
  for (int msk = 1; msk < 64; msk <<= 1) mx = fmaxf(mx, __shfl_xor(mx, msk, 64));
  if ((tid & 63) == 0) redm[tid >> 6] = mx;
  __syncthreads();
  mx = fmaxf(fmaxf(redm[0], redm[1]), fmaxf(redm[2], redm[3]));

  float ex[8], sum = 0.f;
  #pragma unroll
  for (int i = 0; i < 8; ++i) { ex[i] = __expf(vals[i] - mx); sum += ex[i]; }
  #pragma unroll
  for (int msk = 1; msk < 64; msk <<= 1) sum += __shfl_xor(sum, msk, 64);
  if ((tid & 63) == 0) reds[tid >> 6] = sum;
  __syncthreads();
  sum = reds[0] + reds[1] + reds[2] + reds[3];
  const float r = 1.f / sum;
  #pragma unroll
  for (int i = 0; i < 8; ++i) sc[base + (tid + i * 256) * 16] = ex[i] * r;
}

// ---------------- K5: single-pass PV -> out, 256 blocks -------------------
__global__ __launch_bounds__(256) void k_pv(
    const float* __restrict__ values, const float* __restrict__ sc,
    float* __restrict__ out)
{
  __shared__ float lds[2048];                // 8 KB
  const int tid = threadIdx.x;
  const int nc = blockIdx.x & 31, b = blockIdx.x >> 5;
  const int n = tid & 15, kg = tid >> 4;
  const int l = tid & 63, w = tid >> 6;
  const int n0 = nc * 16;

  float acc[16];
  #pragma unroll
  for (int q = 0; q < 16; ++q) acc[q] = 0.f;

  for (int kc = 0; kc < 16; ++kc) {
    __syncthreads();
    const float* ssrc = sc + (size_t)(b * 2048 + kc * 128) * 16;
    *(float4*)&lds[tid * 8]     = *(const float4*)&ssrc[tid * 8];
    *(float4*)&lds[tid * 8 + 4] = *(const float4*)&ssrc[tid * 8 + 4];
    __syncthreads();
    const float* vb = values + ((size_t)(b * 2048 + kc * 128 + kg * 8)) * 512 + n0 + n;
    #pragma unroll
    for (int k2 = 0; k2 < 8; ++k2) {
      const float v = vb[(size_t)k2 * 512];
      const float* sr = &lds[(kg * 8 + k2) * 16];
      #pragma unroll
      for (int qq = 0; qq < 4; ++qq) {
        const float4 s4 = *(const float4*)&sr[qq * 4];
        acc[qq*4+0] = fmaf(v, s4.x, acc[qq*4+0]);
        acc[qq*4+1] = fmaf(v, s4.y, acc[qq*4+1]);
        acc[qq*4+2] = fmaf(v, s4.z, acc[qq*4+2]);
        acc[qq*4+3] = fmaf(v, s4.w, acc[qq*4+3]);
      }
    }
  }
  // reduce kg within wave (4 kg-groups per wave): lanes l, l^16, l^32 share n
  #pragma unroll
  for (int q = 0; q < 16; ++q) {
    acc[q] += __shfl_xor(acc[q], 16, 64);
    acc[q] += __shfl_xor(acc[q], 32, 64);
  }
  __syncthreads();
  if (l < 16) {
    #pragma unroll
    for (int q = 0; q < 16; ++q) lds[w * 256 + q * 16 + l] = acc[q];
  }
  __syncthreads();
  const int q = tid >> 4, nn = tid & 15;
  const float s = (lds[q * 16 + nn] + lds[256 + q * 16 + nn]) +
                  (lds[512 + q * 16 + nn] + lds[768 + q * 16 + nn]);
  out[((size_t)(b * 16 + q)) * 512 + n0 + nn] = s;
}

extern "C" void kernel_launch(void* const* d_in, const int* in_sizes, int n_in,
                              void* d_out, int out_size, void* d_ws, size_t ws_size,
                              hipStream_t stream)
{
  const float* query  = (const float*)d_in[0];
  const float* keys   = (const float*)d_in[1];
  const float* values = (const float*)d_in[2];
  const float* W      = (const float*)d_in[3];
  const float* w_bias = (const float*)d_in[4];
  const float* vw     = (const float*)d_in[5];
  // d_in[6] (v_bias) + sum_h v_h are (k)-constant logit shifts -> softmax-invariant.

  char* ws = (char*)d_ws;
  unsigned short* keys_bf = (unsigned short*)(ws + OFF_KEYS_BF);
  unsigned short* wk_bf   = (unsigned short*)(ws + OFF_WK_BF);
  float* eqb    = (float*)(ws + OFF_EQB);
  float* e_part = (float*)(ws + OFF_EPART);
  float* sc     = (float*)(ws + OFF_SC);
  // qw_bf (query 128 rows + Wq 512 rows, bf16 = 640KB) aliases e_part region
  // (4MB); qw_bf is dead before k_fused writes e_part.
  unsigned short* qw_bf = (unsigned short*)(ws + OFF_EPART);

  hipLaunchKernelGGL(k_convq, dim3(160), dim3(256), 0, stream, query, W, qw_bf);
  hipLaunchKernelGGL(k_convert, dim3(4224), dim3(256), 0, stream,
                     keys, W, keys_bf, wk_bf);
  hipLaunchKernelGGL(k_qgemm, dim3(16), dim3(256), 0, stream, qw_bf, eqb);
  hipLaunchKernelGGL(k_fused, dim3(128, 4), dim3(256), 0, stream,
                     keys_bf, wk_bf, w_bias, eqb, vw, e_part);
  hipLaunchKernelGGL(k_softmax, dim3(128), dim3(256), 0, stream, e_part, sc);
  hipLaunchKernelGGL(k_pv, dim3(256), dim3(256), 0, stream, values, sc, (float*)d_out);
}

// Round 10
// 91.274 us; speedup vs baseline: 1.2021x; 1.0295x over previous
//
#include <hip/hip_runtime.h>
#include <cstddef>

using bf16x8  = __attribute__((ext_vector_type(8))) short;
using short4v = __attribute__((ext_vector_type(4))) short;
using f32x4   = __attribute__((ext_vector_type(4))) float;
using ushort8 = __attribute__((ext_vector_type(8))) unsigned short;

#define GLL16(gp, lp) __builtin_amdgcn_global_load_lds( \
    (const __attribute__((address_space(1))) unsigned int*)(const void*)(gp), \
    (__attribute__((address_space(3))) unsigned int*)(void*)(lp), 16, 0, 0)

__device__ __forceinline__ float exp2_f(float x){ float r; asm("v_exp_f32 %0, %1" : "=v"(r) : "v"(x)); return r; }
__device__ __forceinline__ float rcp_f (float x){ float r; asm("v_rcp_f32 %0, %1" : "=v"(r) : "v"(x)); return r; }
__device__ __forceinline__ unsigned short f2bf(float f){
  unsigned int u = __float_as_uint(f);
  u = u + 0x7FFFu + ((u >> 16) & 1u);
  return (unsigned short)(u >> 16);
}
__device__ __forceinline__ float bf2f(unsigned short s){
  return __uint_as_float(((unsigned int)s) << 16);
}

// problem sizes: B=8 Q=16 KV=2048 NQ=NK=NV=H=512
#define KEYS_N   8388608
#define WK_N     262144
#define QW_N     327680
#define SCALE_2LOG2E 2.885390081777927f   // 2*log2(e): exp2(x*S) = exp(2x)

// workspace layout (bytes); total = 22,806,528
#define OFF_KEYS_BF   0u          // 16384x512 bf16
#define OFF_WK_BF     16777216u   // 512x512 bf16
#define OFF_EQB       17301504u   // 128x512 f32: exp2(S*q_part)
#define OFF_EPART     17563648u   // 4 x [8*2048*16] f32 partial logits
#define OFF_SC        21757952u   // 8x2048x16 f32 scores

// ---------------- K1: f32 -> bf16 conversion (keys + Wk + query/Wq) -------
// grid 4384: [0,4096) keys, [4096,4224) wk, [4224,4384) qw (query rows 0-127,
// Wq rows 128-639 of qw_bf).
__global__ __launch_bounds__(256) void k_convert(
    const float* __restrict__ keys, const float* __restrict__ W,
    const float* __restrict__ query,
    unsigned short* __restrict__ keys_bf, unsigned short* __restrict__ wk_bf,
    unsigned short* __restrict__ qw_bf)
{
  int idx = (blockIdx.x * 256 + threadIdx.x) * 8;
  const float* src;
  unsigned short* dst;
  if (idx < KEYS_N) { src = keys + idx; dst = keys_bf + idx; }
  else if (idx < KEYS_N + WK_N) {
    int e = idx - KEYS_N;                    // wk[h][c]
    src = W + (size_t)(e >> 9) * 1024 + 512 + (e & 511);
    dst = wk_bf + e;
  } else {
    int e = idx - (KEYS_N + WK_N);           // qw: query then Wq
    if (e < 65536) src = query + e;
    else { int f = e - 65536; src = W + (size_t)(f >> 9) * 1024 + (f & 511); }
    dst = qw_bf + e;
  }
  float4 a = *(const float4*)src;
  float4 b = *(const float4*)(src + 4);
  ushort8 o;
  o[0]=f2bf(a.x); o[1]=f2bf(a.y); o[2]=f2bf(a.z); o[3]=f2bf(a.w);
  o[4]=f2bf(b.x); o[5]=f2bf(b.y); o[6]=f2bf(b.z); o[7]=f2bf(b.w);
  *(ushort8*)dst = o;
}

// ---------------- K2: q-GEMM: eqb = exp2(S*query·Wq^T), 16 blocks ---------
__global__ __launch_bounds__(256) void k_qgemm(
    const unsigned short* __restrict__ query_bf, float* __restrict__ eqb)
{
  __shared__ struct { short A[128*64]; short B[32*64]; } g;
  const int tid = threadIdx.x;
  const int l = tid & 63, w = tid >> 6;
  const int n0 = blockIdx.x * 32;
  const int wm = w & 1, wn = w >> 1;
  const int fr = l & 15, fg = l >> 4;
  const int axk = fr & 7;

  f32x4 acc[4];
  #pragma unroll
  for (int i = 0; i < 4; ++i) acc[i] = (f32x4){0.f,0.f,0.f,0.f};

  const int srow8 = (l >> 3);
  const int schk  = ((l & 7) ^ srow8) * 8;

  for (int kt = 0; kt < 8; ++kt) {
    const int k0 = kt * 64;
    #pragma unroll
    for (int r = 0; r < 4; ++r)
      GLL16(query_bf + (size_t)(r * 32 + w * 8 + srow8) * 512 + k0 + schk,
            &g.A[r * 2048 + w * 512]);
    GLL16(query_bf + (size_t)(128 + n0 + w * 8 + srow8) * 512 + k0 + schk,
          &g.B[w * 512]);
    __syncthreads();
    #pragma unroll
    for (int ks = 0; ks < 2; ++ks) {
      bf16x8 af[4], bfv;
      #pragma unroll
      for (int i = 0; i < 4; ++i)
        af[i] = *(const bf16x8*)&g.A[(wm*64 + i*16 + fr) * 64 + ((ks*4 + fg) ^ axk) * 8];
      bfv = *(const bf16x8*)&g.B[(wn*16 + fr) * 64 + ((ks*4 + fg) ^ axk) * 8];
      #pragma unroll
      for (int i = 0; i < 4; ++i)
        acc[i] = __builtin_amdgcn_mfma_f32_16x16x32_bf16(af[i], bfv, acc[i], 0, 0, 0);
    }
    __syncthreads();
  }
  const int gh = n0 + wn*16 + fr;
  #pragma unroll
  for (int i = 0; i < 4; ++i)
    #pragma unroll
    for (int r = 0; r < 4; ++r) {
      const int gm = wm*64 + i*16 + fg*4 + r;
      eqb[gm * 512 + gh] = exp2_f(acc[i][r] * SCALE_2LOG2E);
    }
}

// ---------------- K3: FUSED k-GEMM + energy -------------------------------
// Tile M=64 x N=128, grid (256 by, 4 hc) = 1024 blocks -> 4 blocks/CU.
// 2x2 waves of 32m x 64n: acc[2][4] = 32 VGPR (fits 128-cap of bounds(256,4)).
// LDS 32KB: union{A 8KB + B 16KB, ekbf[64][128] bf16 16KB} + eqs 8KB.
struct FusedSM {
  union {
    struct { short A[64*64]; short B[128*64]; } g;  // 24 KB, BK=64 single-buf
    unsigned short ekbf[64 * 128];                  // 16 KB
  } u;
  float eqs[16 * 128];                              // 8 KB
};

__global__ __launch_bounds__(256, 4) void k_fused(
    const unsigned short* __restrict__ keys_bf, const unsigned short* __restrict__ wk_bf,
    const float* __restrict__ w_bias, const float* __restrict__ eqb,
    const float* __restrict__ vw, float* __restrict__ e_part)
{
  __shared__ FusedSM sm;
  const int tid = threadIdx.x;
  const int l = tid & 63, w = tid >> 6;
  const int by = blockIdx.x;              // 0..255 m-tile (64 k-rows)
  const int hc = blockIdx.y;              // 0..3 h-chunk
  const int h0 = hc * 128;
  const int b  = by >> 5;                 // 32 m-tiles per batch

  // stage eqs [16 q][128 h] (disjoint LDS region)
  {
    const int q = tid >> 4, c0 = (tid & 15) * 8;
    const float* src = eqb + (size_t)(b * 16 + q) * 512 + h0 + c0;
    *(float4*)&sm.eqs[q * 128 + c0]     = *(const float4*)src;
    *(float4*)&sm.eqs[q * 128 + c0 + 4] = *(const float4*)(src + 4);
  }

  const unsigned short* Aptr = keys_bf + (size_t)by * 64 * 512;
  const unsigned short* Bptr = wk_bf + (size_t)h0 * 512;

  const int sr8  = l >> 3;                 // row within 8-row group
  const int scol = ((l & 7) ^ sr8) * 8;    // pre-swizzled source 16B chunk
  const int wm = w >> 1, wn = w & 1;
  const int fr = l & 15, fg = l >> 4;
  const int axk = fr & 7;

  f32x4 acc[2][4];
  #pragma unroll
  for (int i = 0; i < 2; ++i)
    #pragma unroll
    for (int j = 0; j < 4; ++j) acc[i][j] = (f32x4){0.f,0.f,0.f,0.f};

  for (int kt = 0; kt < 8; ++kt) {
    const int k0 = kt * 64;
    #pragma unroll
    for (int r = 0; r < 2; ++r)
      GLL16(Aptr + (w * 16 + r * 8 + sr8) * 512 + k0 + scol, &sm.u.g.A[w * 1024 + r * 512]);
    #pragma unroll
    for (int r = 0; r < 4; ++r)
      GLL16(Bptr + (w * 32 + r * 8 + sr8) * 512 + k0 + scol, &sm.u.g.B[w * 2048 + r * 512]);
    __syncthreads();                       // loads landed
    #pragma unroll
    for (int ks = 0; ks < 2; ++ks) {
      bf16x8 af[2], bfv[4];
      #pragma unroll
      for (int i = 0; i < 2; ++i)
        af[i]  = *(const bf16x8*)&sm.u.g.A[(wm*32 + i*16 + fr) * 64 + ((ks*4 + fg) ^ axk) * 8];
      #pragma unroll
      for (int j = 0; j < 4; ++j)
        bfv[j] = *(const bf16x8*)&sm.u.g.B[(wn*64 + j*16 + fr) * 64 + ((ks*4 + fg) ^ axk) * 8];
      #pragma unroll
      for (int i = 0; i < 2; ++i)
        #pragma unroll
        for (int j = 0; j < 4; ++j)
          acc[i][j] = __builtin_amdgcn_mfma_f32_16x16x32_bf16(af[i], bfv[j], acc[i][j], 0, 0, 0);
    }
    __syncthreads();                       // reads done before next overwrite
  }

  // acc -> ekbf (bf16), swizzled chunk' = (col>>3) ^ (row&15)
  #pragma unroll
  for (int j = 0; j < 4; ++j) {
    const int col = wn*64 + j*16 + fr;
    const float bias = w_bias[h0 + col];
    const int chunk = col >> 3, coff = col & 7;
    #pragma unroll
    for (int i = 0; i < 2; ++i)
      #pragma unroll
      for (int r = 0; r < 4; ++r) {
        const int row = wm*32 + i*16 + fg*4 + r;       // row&15 = fg*4+r
        const float ev = exp2_f((acc[i][j][r] + bias) * SCALE_2LOG2E);
        sm.u.ekbf[row * 128 + ((chunk ^ (fg*4 + r)) << 3) + coff] = f2bf(ev);
      }
  }
  // v weights (pre-scaled by -2); lane owns h {s*32+g*4+u, s*32+16+g*4+u}
  const int g = l & 3, kl = l >> 2;
  float vv[32];
  #pragma unroll
  for (int s = 0; s < 4; ++s) {
    const float4 a0 = *(const float4*)(vw + h0 + s*32 + g*4);
    const float4 a1 = *(const float4*)(vw + h0 + s*32 + 16 + g*4);
    vv[s*8+0]=-2.f*a0.x; vv[s*8+1]=-2.f*a0.y; vv[s*8+2]=-2.f*a0.z; vv[s*8+3]=-2.f*a0.w;
    vv[s*8+4]=-2.f*a1.x; vv[s*8+5]=-2.f*a1.y; vv[s*8+6]=-2.f*a1.z; vv[s*8+7]=-2.f*a1.w;
  }
  __syncthreads();

  // energy: single pass, wave w owns rows w*16..w*16+15 (kl), 4 h-groups (g)
  {
    const int lr = w * 16 + kl;                   // lr&15 = kl
    float ek[32];
    #pragma unroll
    for (int s = 0; s < 4; ++s)
      #pragma unroll
      for (int hf = 0; hf < 2; ++hf) {
        const int ck = (4*s + 2*hf + (g >> 1)) ^ kl;
        const short4v v4 = *(const short4v*)&sm.u.ekbf[lr * 128 + (ck << 3) + (g & 1) * 4];
        ek[s*8 + hf*4 + 0] = bf2f((unsigned short)v4[0]);
        ek[s*8 + hf*4 + 1] = bf2f((unsigned short)v4[1]);
        ek[s*8 + hf*4 + 2] = bf2f((unsigned short)v4[2]);
        ek[s*8 + hf*4 + 3] = bf2f((unsigned short)v4[3]);
      }
    const size_t epbase = (size_t)hc * 262144 + ((size_t)(by * 64 + lr)) * 16;
    #pragma unroll 2
    for (int q = 0; q < 16; ++q) {
      float a0 = 0.f, a1 = 0.f;
      #pragma unroll
      for (int s = 0; s < 4; ++s) {
        const float* er = &sm.eqs[q * 128 + s * 32 + g * 4];
        const float4 E0 = *(const float4*)er;
        const float4 E1 = *(const float4*)(er + 16);
        a0 = fmaf(vv[s*8+0], rcp_f(fmaf(ek[s*8+0], E0.x, 1.f)), a0);
        a1 = fmaf(vv[s*8+1], rcp_f(fmaf(ek[s*8+1], E0.y, 1.f)), a1);
        a0 = fmaf(vv[s*8+2], rcp_f(fmaf(ek[s*8+2], E0.z, 1.f)), a0);
        a1 = fmaf(vv[s*8+3], rcp_f(fmaf(ek[s*8+3], E0.w, 1.f)), a1);
        a0 = fmaf(vv[s*8+4], rcp_f(fmaf(ek[s*8+4], E1.x, 1.f)), a0);
        a1 = fmaf(vv[s*8+5], rcp_f(fmaf(ek[s*8+5], E1.y, 1.f)), a1);
        a0 = fmaf(vv[s*8+6], rcp_f(fmaf(ek[s*8+6], E1.z, 1.f)), a0);
        a1 = fmaf(vv[s*8+7], rcp_f(fmaf(ek[s*8+7], E1.w, 1.f)), a1);
      }
      float a = a0 + a1;
      a += __shfl_xor(a, 1, 64);
      a += __shfl_xor(a, 2, 64);
      if (g == 0) e_part[epbase + q] = a;
    }
  }
}

// ---------------- K4: softmax over k: sum 4 partials, normalize -----------
__global__ __launch_bounds__(256) void k_softmax(
    const float* __restrict__ e_part, float* __restrict__ sc)
{
  const int b = blockIdx.x >> 4, q = blockIdx.x & 15;
  const int base = b * 32768 + q;           // stride 16 over k
  const int tid = threadIdx.x;
  __shared__ float redm[4], reds[4];

  float vals[8];
  float mx = -1e30f;
  #pragma unroll
  for (int i = 0; i < 8; ++i) {
    const int x = base + (tid + i * 256) * 16;
    vals[i] = (e_part[x] + e_part[x + 262144]) + (e_part[x + 524288] + e_part[x + 786432]);
    mx = fmaxf(mx, vals[i]);
  }
  #pragma unroll
  for (int msk = 1; msk < 64; msk <<= 1) mx = fmaxf(mx, __shfl_xor(mx, msk, 64));
  if ((tid & 63) == 0) redm[tid >> 6] = mx;
  __syncthreads();
  mx = fmaxf(fmaxf(redm[0], redm[1]), fmaxf(redm[2], redm[3]));

  float ex[8], sum = 0.f;
  #pragma unroll
  for (int i = 0; i < 8; ++i) { ex[i] = __expf(vals[i] - mx); sum += ex[i]; }
  #pragma unroll
  for (int msk = 1; msk < 64; msk <<= 1) sum += __shfl_xor(sum, msk, 64);
  if ((tid & 63) == 0) reds[tid >> 6] = sum;
  __syncthreads();
  sum = reds[0] + reds[1] + reds[2] + reds[3];
  const float r = 1.f / sum;
  #pragma unroll
  for (int i = 0; i < 8; ++i) sc[base + (tid + i * 256) * 16] = ex[i] * r;
}

// ---------------- K5: single-pass PV -> out, 256 blocks -------------------
__global__ __launch_bounds__(256) void k_pv(
    const float* __restrict__ values, const float* __restrict__ sc,
    float* __restrict__ out)
{
  __shared__ float lds[2048];                // 8 KB
  const int tid = threadIdx.x;
  const int nc = blockIdx.x & 31, b = blockIdx.x >> 5;
  const int n = tid & 15, kg = tid >> 4;
  const int l = tid & 63, w = tid >> 6;
  const int n0 = nc * 16;

  float acc[16];
  #pragma unroll
  for (int q = 0; q < 16; ++q) acc[q] = 0.f;

  for (int kc = 0; kc < 16; ++kc) {
    __syncthreads();
    const float* ssrc = sc + (size_t)(b * 2048 + kc * 128) * 16;
    *(float4*)&lds[tid * 8]     = *(const float4*)&ssrc[tid * 8];
    *(float4*)&lds[tid * 8 + 4] = *(const float4*)&ssrc[tid * 8 + 4];
    __syncthreads();
    const float* vb = values + ((size_t)(b * 2048 + kc * 128 + kg * 8)) * 512 + n0 + n;
    #pragma unroll
    for (int k2 = 0; k2 < 8; ++k2) {
      const float v = vb[(size_t)k2 * 512];
      const float* sr = &lds[(kg * 8 + k2) * 16];
      #pragma unroll
      for (int qq = 0; qq < 4; ++qq) {
        const float4 s4 = *(const float4*)&sr[qq * 4];
        acc[qq*4+0] = fmaf(v, s4.x, acc[qq*4+0]);
        acc[qq*4+1] = fmaf(v, s4.y, acc[qq*4+1]);
        acc[qq*4+2] = fmaf(v, s4.z, acc[qq*4+2]);
        acc[qq*4+3] = fmaf(v, s4.w, acc[qq*4+3]);
      }
    }
  }
  // reduce kg within wave: lanes l, l^16, l^32 share n
  #pragma unroll
  for (int q = 0; q < 16; ++q) {
    acc[q] += __shfl_xor(acc[q], 16, 64);
    acc[q] += __shfl_xor(acc[q], 32, 64);
  }
  __syncthreads();
  if (l < 16) {
    #pragma unroll
    for (int q = 0; q < 16; ++q) lds[w * 256 + q * 16 + l] = acc[q];
  }
  __syncthreads();
  const int q = tid >> 4, nn = tid & 15;
  const float s = (lds[q * 16 + nn] + lds[256 + q * 16 + nn]) +
                  (lds[512 + q * 16 + nn] + lds[768 + q * 16 + nn]);
  out[((size_t)(b * 16 + q)) * 512 + n0 + nn] = s;
}

extern "C" void kernel_launch(void* const* d_in, const int* in_sizes, int n_in,
                              void* d_out, int out_size, void* d_ws, size_t ws_size,
                              hipStream_t stream)
{
  const float* query  = (const float*)d_in[0];
  const float* keys   = (const float*)d_in[1];
  const float* values = (const float*)d_in[2];
  const float* W      = (const float*)d_in[3];
  const float* w_bias = (const float*)d_in[4];
  const float* vw     = (const float*)d_in[5];
  // d_in[6] (v_bias) + sum_h v_h are (k)-constant logit shifts -> softmax-invariant.

  char* ws = (char*)d_ws;
  unsigned short* keys_bf = (unsigned short*)(ws + OFF_KEYS_BF);
  unsigned short* wk_bf   = (unsigned short*)(ws + OFF_WK_BF);
  float* eqb    = (float*)(ws + OFF_EQB);
  float* e_part = (float*)(ws + OFF_EPART);
  float* sc     = (float*)(ws + OFF_SC);
  // qw_bf (query 128 rows + Wq 512 rows, bf16 = 640KB) aliases e_part region
  // (4MB); qw_bf is dead before k_fused writes e_part.
  unsigned short* qw_bf = (unsigned short*)(ws + OFF_EPART);

  hipLaunchKernelGGL(k_convert, dim3(4384), dim3(256), 0, stream,
                     keys, W, query, keys_bf, wk_bf, qw_bf);
  hipLaunchKernelGGL(k_qgemm, dim3(16), dim3(256), 0, stream, qw_bf, eqb);
  hipLaunchKernelGGL(k_fused, dim3(256, 4), dim3(256), 0, stream,
                     keys_bf, wk_bf, w_bias, eqb, vw, e_part);
  hipLaunchKernelGGL(k_softmax, dim3(128), dim3(256), 0, stream, e_part, sc);
  hipLaunchKernelGGL(k_pv, dim3(256), dim3(256), 0, stream, values, sc, (float*)d_out);
}

// Round 11
// 87.520 us; speedup vs baseline: 1.2537x; 1.0429x over previous
//
#include <hip/hip_runtime.h>
#include <cstddef>

using bf16x8  = __attribute__((ext_vector_type(8))) short;
using short4v = __attribute__((ext_vector_type(4))) short;
using f32x4   = __attribute__((ext_vector_type(4))) float;
using ushort8 = __attribute__((ext_vector_type(8))) unsigned short;

#define GLL16(gp, lp) __builtin_amdgcn_global_load_lds( \
    (const __attribute__((address_space(1))) unsigned int*)(const void*)(gp), \
    (__attribute__((address_space(3))) unsigned int*)(void*)(lp), 16, 0, 0)

__device__ __forceinline__ float exp2_f(float x){ float r; asm("v_exp_f32 %0, %1" : "=v"(r) : "v"(x)); return r; }
__device__ __forceinline__ float rcp_f (float x){ float r; asm("v_rcp_f32 %0, %1" : "=v"(r) : "v"(x)); return r; }
__device__ __forceinline__ unsigned pk2(float lo, float hi){
  unsigned r; asm("v_cvt_pk_bf16_f32 %0, %1, %2" : "=v"(r) : "v"(lo), "v"(hi)); return r;
}
__device__ __forceinline__ unsigned short f2bf(float f){
  unsigned int u = __float_as_uint(f);
  u = u + 0x7FFFu + ((u >> 16) & 1u);
  return (unsigned short)(u >> 16);
}
__device__ __forceinline__ float bf2f(unsigned short s){
  return __uint_as_float(((unsigned int)s) << 16);
}

// problem sizes: B=8 Q=16 KV=2048 NQ=NK=NV=H=512
#define KEYS_N   8388608
#define WK_N     262144
#define CONV_BLOCKS 4224          // 4096 keys + 128 wk; +16 qgemm blocks
#define SCALE_2LOG2E 2.885390081777927f   // 2*log2(e): exp2(x*S) = exp(2x)

// workspace layout (bytes); total = 22,806,528
#define OFF_KEYS_BF   0u          // 16384x512 bf16
#define OFF_WK_BF     16777216u   // 512x512 bf16
#define OFF_EQB       17301504u   // 128x512 f32: exp2(S*q_part)
#define OFF_EPART     17563648u   // 4 x [8*2048*16] f32 partial logits
#define OFF_SC        21757952u   // 8x2048x16 f32 scores

// ---------------- K1: convert (keys+Wk -> bf16) ∥ q-GEMM ------------------
// blocks [0,4224): bf16 convert. blocks [4224,4240): f32-direct q-GEMM
// (M=128 query rows, N=32 Wq rows, K=512, BK=32 reg-staged) -> eqb.
// The 16 qgemm blocks run concurrently with the BW-bound convert stream.
__global__ __launch_bounds__(256) void k_convert(
    const float* __restrict__ keys, const float* __restrict__ W,
    const float* __restrict__ query,
    unsigned short* __restrict__ keys_bf, unsigned short* __restrict__ wk_bf,
    float* __restrict__ eqb)
{
  __shared__ short qg[128*32 + 32*32];     // 10 KB (qgemm branch only)
  if (blockIdx.x >= CONV_BLOCKS) {
    const int nb = blockIdx.x - CONV_BLOCKS;     // 0..15
    const int n0 = nb * 32;
    const int tid = threadIdx.x;
    const int l = tid & 63, w = tid >> 6;
    short* A  = qg;                 // [128][32] swizzled
    short* Bs = qg + 4096;          // [32][32] swizzled
    const int sub = tid >> 3;       // 0..31
    const int c4  = (tid & 7) * 4;  // col within 32
    const int wm = w & 1, wn = w >> 1;
    const int fr = l & 15, fg = l >> 4;

    f32x4 acc[4];
    #pragma unroll
    for (int i = 0; i < 4; ++i) acc[i] = (f32x4){0.f,0.f,0.f,0.f};

    for (int kt = 0; kt < 16; ++kt) {
      const int k0 = kt * 32;
      float4 a4[4];
      #pragma unroll
      for (int m = 0; m < 4; ++m)
        a4[m] = *(const float4*)(query + (size_t)(m * 32 + sub) * 512 + k0 + c4);
      const float4 b4 = *(const float4*)(W + (size_t)(n0 + sub) * 1024 + k0 + c4);
      __syncthreads();              // prior reads done before overwrite
      #pragma unroll
      for (int m = 0; m < 4; ++m) {
        const int row = m * 32 + sub;
        const int o = row * 32 + (((c4 >> 3) ^ ((row >> 1) & 3)) << 3) + (c4 & 7);
        *(uint2*)&A[o] = make_uint2(pk2(a4[m].x, a4[m].y), pk2(a4[m].z, a4[m].w));
      }
      {
        const int o = sub * 32 + (((c4 >> 3) ^ ((sub >> 1) & 3)) << 3) + (c4 & 7);
        *(uint2*)&Bs[o] = make_uint2(pk2(b4.x, b4.y), pk2(b4.z, b4.w));
      }
      __syncthreads();
      bf16x8 af[4], bfv;
      #pragma unroll
      for (int i = 0; i < 4; ++i) {
        const int ar = wm*64 + i*16 + fr;
        af[i] = *(const bf16x8*)&A[ar*32 + ((fg ^ ((ar>>1)&3)) << 3)];
      }
      const int br = wn*16 + fr;
      bfv = *(const bf16x8*)&Bs[br*32 + ((fg ^ ((br>>1)&3)) << 3)];
      #pragma unroll
      for (int i = 0; i < 4; ++i)
        acc[i] = __builtin_amdgcn_mfma_f32_16x16x32_bf16(af[i], bfv, acc[i], 0, 0, 0);
    }
    const int gh = n0 + wn*16 + fr;
    #pragma unroll
    for (int i = 0; i < 4; ++i)
      #pragma unroll
      for (int r = 0; r < 4; ++r) {
        const int gm = wm*64 + i*16 + fg*4 + r;
        eqb[gm * 512 + gh] = exp2_f(acc[i][r] * SCALE_2LOG2E);
      }
    return;
  }
  // ---- convert path
  int idx = (blockIdx.x * 256 + threadIdx.x) * 8;
  const float* src;
  unsigned short* dst;
  if (idx < KEYS_N) { src = keys + idx; dst = keys_bf + idx; }
  else {
    int e = idx - KEYS_N;                    // wk[h][c]
    src = W + (size_t)(e >> 9) * 1024 + 512 + (e & 511);
    dst = wk_bf + e;
  }
  float4 a = *(const float4*)src;
  float4 b = *(const float4*)(src + 4);
  ushort8 o;
  o[0]=f2bf(a.x); o[1]=f2bf(a.y); o[2]=f2bf(a.z); o[3]=f2bf(a.w);
  o[4]=f2bf(b.x); o[5]=f2bf(b.y); o[6]=f2bf(b.z); o[7]=f2bf(b.w);
  *(ushort8*)dst = o;
}

// ---------------- K2: FUSED k-GEMM + energy (r9 base + dual-row energy) ---
// LDS 40KB: union{staging A+B 32KB, ekbf[128][128] bf16 32KB} + eqs 8KB.
struct FusedSM {
  union {
    struct { short A[8192]; short B[8192]; } g;   // 32 KB single-buffer BK=64
    unsigned short ekbf[128 * 128];               // 32 KB
  } u;
  float eqs[16 * 128];                            // 8 KB
};

__global__ __launch_bounds__(256, 3) void k_fused(
    const unsigned short* __restrict__ keys_bf, const unsigned short* __restrict__ wk_bf,
    const float* __restrict__ w_bias, const float* __restrict__ eqb,
    const float* __restrict__ vw, float* __restrict__ e_part)
{
  __shared__ FusedSM sm;
  const int tid = threadIdx.x;
  const int l = tid & 63, w = tid >> 6;
  const int by = blockIdx.x;              // 0..127 m-tile (128 k-rows)
  const int hc = blockIdx.y;              // 0..3 h-chunk
  const int h0 = hc * 128;
  const int b  = by >> 4;

  // stage eqs [16 q][128 h] (disjoint LDS region)
  {
    const int q = tid >> 4, c0 = (tid & 15) * 8;
    const float* src = eqb + (size_t)(b * 16 + q) * 512 + h0 + c0;
    *(float4*)&sm.eqs[q * 128 + c0]     = *(const float4*)src;
    *(float4*)&sm.eqs[q * 128 + c0 + 4] = *(const float4*)(src + 4);
  }

  const unsigned short* Aptr = keys_bf + (size_t)by * 128 * 512;
  const unsigned short* Bptr = wk_bf + (size_t)h0 * 512;

  const int srow = w * 32 + (l >> 3);
  const int scol = ((l & 7) ^ (l >> 3)) * 8;
  const int wm = w >> 1, wn = w & 1;
  const int fr = l & 15, fg = l >> 4;
  const int axk = fr & 7;

  f32x4 acc[4][4];
  #pragma unroll
  for (int i = 0; i < 4; ++i)
    #pragma unroll
    for (int j = 0; j < 4; ++j) acc[i][j] = (f32x4){0.f,0.f,0.f,0.f};

  for (int kt = 0; kt < 8; ++kt) {
    const int k0 = kt * 64;
    #pragma unroll
    for (int r = 0; r < 4; ++r) {
      GLL16(Aptr + (srow + r * 8) * 512 + k0 + scol, &sm.u.g.A[w * 2048 + r * 512]);
      GLL16(Bptr + (srow + r * 8) * 512 + k0 + scol, &sm.u.g.B[w * 2048 + r * 512]);
    }
    __syncthreads();                       // loads landed
    #pragma unroll
    for (int ks = 0; ks < 2; ++ks) {
      bf16x8 af[4], bfv[4];
      #pragma unroll
      for (int i = 0; i < 4; ++i) {
        af[i]  = *(const bf16x8*)&sm.u.g.A[(wm*64 + i*16 + fr) * 64 + ((ks*4 + fg) ^ axk) * 8];
        bfv[i] = *(const bf16x8*)&sm.u.g.B[(wn*64 + i*16 + fr) * 64 + ((ks*4 + fg) ^ axk) * 8];
      }
      #pragma unroll
      for (int i = 0; i < 4; ++i)
        #pragma unroll
        for (int j = 0; j < 4; ++j)
          acc[i][j] = __builtin_amdgcn_mfma_f32_16x16x32_bf16(af[i], bfv[j], acc[i][j], 0, 0, 0);
    }
    __syncthreads();                       // reads done before next overwrite
  }

  // all waves: acc -> ekbf (bf16), swizzled chunk' = (col>>3) ^ (row&15)
  #pragma unroll
  for (int j = 0; j < 4; ++j) {
    const int col = wn*64 + j*16 + fr;
    const float bias = w_bias[h0 + col];
    const int chunk = col >> 3, coff = col & 7;
    #pragma unroll
    for (int i = 0; i < 4; ++i)
      #pragma unroll
      for (int r = 0; r < 4; ++r) {
        const int row = wm*64 + i*16 + fg*4 + r;       // row&15 = fg*4+r
        const float ev = exp2_f((acc[i][j][r] + bias) * SCALE_2LOG2E);
        sm.u.ekbf[row * 128 + ((chunk ^ (fg*4 + r)) << 3) + coff] = f2bf(ev);
      }
  }
  // v weights (pre-scaled by -2); lane owns h {s*32+g*4+u, s*32+16+g*4+u}
  const int g = l & 3, kl = l >> 2;
  float vv[32];
  #pragma unroll
  for (int s = 0; s < 4; ++s) {
    const float4 a0 = *(const float4*)(vw + h0 + s*32 + g*4);
    const float4 a1 = *(const float4*)(vw + h0 + s*32 + 16 + g*4);
    vv[s*8+0]=-2.f*a0.x; vv[s*8+1]=-2.f*a0.y; vv[s*8+2]=-2.f*a0.z; vv[s*8+3]=-2.f*a0.w;
    vv[s*8+4]=-2.f*a1.x; vv[s*8+5]=-2.f*a1.y; vv[s*8+6]=-2.f*a1.z; vv[s*8+7]=-2.f*a1.w;
  }
  __syncthreads();

  // energy: wave w owns rows {w*32+kl, w*32+16+kl}; one eqs pass serves both
  {
    const int lr0 = w * 32 + kl;                 // lr0&15 = kl
    const int lr1 = lr0 + 16;                    // lr1&15 = kl (same ck)
    float ek0[32], ek1[32];
    #pragma unroll
    for (int s = 0; s < 4; ++s)
      #pragma unroll
      for (int hf = 0; hf < 2; ++hf) {
        const int ck = (4*s + 2*hf + (g >> 1)) ^ kl;
        const short4v v40 = *(const short4v*)&sm.u.ekbf[lr0 * 128 + (ck << 3) + (g & 1) * 4];
        const short4v v41 = *(const short4v*)&sm.u.ekbf[lr1 * 128 + (ck << 3) + (g & 1) * 4];
        #pragma unroll
        for (int u = 0; u < 4; ++u) {
          ek0[s*8 + hf*4 + u] = bf2f((unsigned short)v40[u]);
          ek1[s*8 + hf*4 + u] = bf2f((unsigned short)v41[u]);
        }
      }
    const size_t ep0 = (size_t)hc * 262144 + ((size_t)(by * 128 + lr0)) * 16;
    const size_t ep1 = (size_t)hc * 262144 + ((size_t)(by * 128 + lr1)) * 16;
    #pragma unroll 2
    for (int q = 0; q < 16; ++q) {
      float a00 = 0.f, a01 = 0.f, a10 = 0.f, a11 = 0.f;
      #pragma unroll
      for (int s = 0; s < 4; ++s) {
        const float* er = &sm.eqs[q * 128 + s * 32 + g * 4];
        const float4 E0 = *(const float4*)er;
        const float4 E1 = *(const float4*)(er + 16);
        a00 = fmaf(vv[s*8+0], rcp_f(fmaf(ek0[s*8+0], E0.x, 1.f)), a00);
        a01 = fmaf(vv[s*8+1], rcp_f(fmaf(ek0[s*8+1], E0.y, 1.f)), a01);
        a00 = fmaf(vv[s*8+2], rcp_f(fmaf(ek0[s*8+2], E0.z, 1.f)), a00);
        a01 = fmaf(vv[s*8+3], rcp_f(fmaf(ek0[s*8+3], E0.w, 1.f)), a01);
        a00 = fmaf(vv[s*8+4], rcp_f(fmaf(ek0[s*8+4], E1.x, 1.f)), a00);
        a01 = fmaf(vv[s*8+5], rcp_f(fmaf(ek0[s*8+5], E1.y, 1.f)), a01);
        a00 = fmaf(vv[s*8+6], rcp_f(fmaf(ek0[s*8+6], E1.z, 1.f)), a00);
        a01 = fmaf(vv[s*8+7], rcp_f(fmaf(ek0[s*8+7], E1.w, 1.f)), a01);
        a10 = fmaf(vv[s*8+0], rcp_f(fmaf(ek1[s*8+0], E0.x, 1.f)), a10);
        a11 = fmaf(vv[s*8+1], rcp_f(fmaf(ek1[s*8+1], E0.y, 1.f)), a11);
        a10 = fmaf(vv[s*8+2], rcp_f(fmaf(ek1[s*8+2], E0.z, 1.f)), a10);
        a11 = fmaf(vv[s*8+3], rcp_f(fmaf(ek1[s*8+3], E0.w, 1.f)), a11);
        a10 = fmaf(vv[s*8+4], rcp_f(fmaf(ek1[s*8+4], E1.x, 1.f)), a10);
        a11 = fmaf(vv[s*8+5], rcp_f(fmaf(ek1[s*8+5], E1.y, 1.f)), a11);
        a10 = fmaf(vv[s*8+6], rcp_f(fmaf(ek1[s*8+6], E1.z, 1.f)), a10);
        a11 = fmaf(vv[s*8+7], rcp_f(fmaf(ek1[s*8+7], E1.w, 1.f)), a11);
      }
      float r0 = a00 + a01;
      r0 += __shfl_xor(r0, 1, 64);
      r0 += __shfl_xor(r0, 2, 64);
      float r1 = a10 + a11;
      r1 += __shfl_xor(r1, 1, 64);
      r1 += __shfl_xor(r1, 2, 64);
      if (g == 0) { e_part[ep0 + q] = r0; e_part[ep1 + q] = r1; }
    }
  }
}

// ---------------- K3: softmax over k: sum 4 partials, normalize -----------
__global__ __launch_bounds__(256) void k_softmax(
    const float* __restrict__ e_part, float* __restrict__ sc)
{
  const int b = blockIdx.x >> 4, q = blockIdx.x & 15;
  const int base = b * 32768 + q;           // stride 16 over k
  const int tid = threadIdx.x;
  __shared__ float redm[4], reds[4];

  float vals[8];
  float mx = -1e30f;
  #pragma unroll
  for (int i = 0; i < 8; ++i) {
    const int x = base + (tid + i * 256) * 16;
    vals[i] = (e_part[x] + e_part[x + 262144]) + (e_part[x + 524288] + e_part[x + 786432]);
    mx = fmaxf(mx, vals[i]);
  }
  #pragma unroll
  for (int msk = 1; msk < 64; msk <<= 1) mx = fmaxf(mx, __shfl_xor(mx, msk, 64));
  if ((tid & 63) == 0) redm[tid >> 6] = mx;
  __syncthreads();
  mx = fmaxf(fmaxf(redm[0], redm[1]), fmaxf(redm[2], redm[3]));

  float ex[8], sum = 0.f;
  #pragma unroll
  for (int i = 0; i < 8; ++i) { ex[i] = __expf(vals[i] - mx); sum += ex[i]; }
  #pragma unroll
  for (int msk = 1; msk < 64; msk <<= 1) sum += __shfl_xor(sum, msk, 64);
  if ((tid & 63) == 0) reds[tid >> 6] = sum;
  __syncthreads();
  sum = reds[0] + reds[1] + reds[2] + reds[3];
  const float r = 1.f / sum;
  #pragma unroll
  for (int i = 0; i < 8; ++i) sc[base + (tid + i * 256) * 16] = ex[i] * r;
}

// ---------------- K4: single-pass PV -> out, 256 blocks x 512 thr ---------
// block (b, nc): 16 n-cols, all 2048 k. thread (kg 0..31, n 0..15):
// acc[16 q] over 64-k slice; 2 shuffles + LDS cross-wave reduce; write out.
__global__ __launch_bounds__(512) void k_pv(
    const float* __restrict__ values, const float* __restrict__ sc,
    float* __restrict__ out)
{
  __shared__ float lds[128 * 20];            // 10 KB (stride-20: 16B-aligned, 2-way max)
  const int tid = threadIdx.x;
  const int nc = blockIdx.x & 31, b = blockIdx.x >> 5;
  const int n = tid & 15, kg = tid >> 4;     // 32 kg x 16 n
  const int l = tid & 63, w = tid >> 6;      // 8 waves
  const int n0 = nc * 16;

  float acc[16];
  #pragma unroll
  for (int q = 0; q < 16; ++q) acc[q] = 0.f;

  for (int kc = 0; kc < 16; ++kc) {
    __syncthreads();
    {
      const float* ssrc = sc + (size_t)(b * 2048 + kc * 128) * 16;
      const int row = tid >> 2, c4 = (tid & 3) * 4;
      *(float4*)&lds[row * 20 + c4] = *(const float4*)&ssrc[row * 16 + c4];
    }
    __syncthreads();
    const float* vb = values + ((size_t)(b * 2048 + kc * 128 + kg * 4)) * 512 + n0 + n;
    #pragma unroll
    for (int k2 = 0; k2 < 4; ++k2) {
      const float v = vb[(size_t)k2 * 512];
      const float* sr = &lds[(kg * 4 + k2) * 20];
      #pragma unroll
      for (int qq = 0; qq < 4; ++qq) {
        const float4 s4 = *(const float4*)&sr[qq * 4];
        acc[qq*4+0] = fmaf(v, s4.x, acc[qq*4+0]);
        acc[qq*4+1] = fmaf(v, s4.y, acc[qq*4+1]);
        acc[qq*4+2] = fmaf(v, s4.z, acc[qq*4+2]);
        acc[qq*4+3] = fmaf(v, s4.w, acc[qq*4+3]);
      }
    }
  }
  // within-wave reduce over kg&3 (lanes l, l^16, l^32 share n)
  #pragma unroll
  for (int q = 0; q < 16; ++q) {
    acc[q] += __shfl_xor(acc[q], 16, 64);
    acc[q] += __shfl_xor(acc[q], 32, 64);
  }
  __syncthreads();
  if (l < 16) {
    #pragma unroll
    for (int q = 0; q < 16; ++q) lds[w * 256 + q * 16 + l] = acc[q];
  }
  __syncthreads();
  if (tid < 256) {
    const int q = tid >> 4, nn = tid & 15;
    float s = 0.f;
    #pragma unroll
    for (int w2 = 0; w2 < 8; ++w2) s += lds[w2 * 256 + q * 16 + nn];
    out[((size_t)(b * 16 + q)) * 512 + n0 + nn] = s;
  }
}

extern "C" void kernel_launch(void* const* d_in, const int* in_sizes, int n_in,
                              void* d_out, int out_size, void* d_ws, size_t ws_size,
                              hipStream_t stream)
{
  const float* query  = (const float*)d_in[0];
  const float* keys   = (const float*)d_in[1];
  const float* values = (const float*)d_in[2];
  const float* W      = (const float*)d_in[3];
  const float* w_bias = (const float*)d_in[4];
  const float* vw     = (const float*)d_in[5];
  // d_in[6] (v_bias) + sum_h v_h are (k)-constant logit shifts -> softmax-invariant.

  char* ws = (char*)d_ws;
  unsigned short* keys_bf = (unsigned short*)(ws + OFF_KEYS_BF);
  unsigned short* wk_bf   = (unsigned short*)(ws + OFF_WK_BF);
  float* eqb    = (float*)(ws + OFF_EQB);
  float* e_part = (float*)(ws + OFF_EPART);
  float* sc     = (float*)(ws + OFF_SC);

  hipLaunchKernelGGL(k_convert, dim3(CONV_BLOCKS + 16), dim3(256), 0, stream,
                     keys, W, query, keys_bf, wk_bf, eqb);
  hipLaunchKernelGGL(k_fused, dim3(128, 4), dim3(256), 0, stream,
                     keys_bf, wk_bf, w_bias, eqb, vw, e_part);
  hipLaunchKernelGGL(k_softmax, dim3(128), dim3(256), 0, stream, e_part, sc);
  hipLaunchKernelGGL(k_pv, dim3(256), dim3(512), 0, stream, values, sc, (float*)d_out);
}

// Round 12
// 85.323 us; speedup vs baseline: 1.2860x; 1.0257x over previous
//
#include <hip/hip_runtime.h>
#include <cstddef>

using bf16x8  = __attribute__((ext_vector_type(8))) short;
using short4v = __attribute__((ext_vector_type(4))) short;
using f32x4   = __attribute__((ext_vector_type(4))) float;
using ushort8 = __attribute__((ext_vector_type(8))) unsigned short;

#define GLL16(gp, lp) __builtin_amdgcn_global_load_lds( \
    (const __attribute__((address_space(1))) unsigned int*)(const void*)(gp), \
    (__attribute__((address_space(3))) unsigned int*)(void*)(lp), 16, 0, 0)

__device__ __forceinline__ float exp2_f(float x){ float r; asm("v_exp_f32 %0, %1" : "=v"(r) : "v"(x)); return r; }
__device__ __forceinline__ float rcp_f (float x){ float r; asm("v_rcp_f32 %0, %1" : "=v"(r) : "v"(x)); return r; }
__device__ __forceinline__ unsigned pk2(float lo, float hi){
  unsigned r; asm("v_cvt_pk_bf16_f32 %0, %1, %2" : "=v"(r) : "v"(lo), "v"(hi)); return r;
}
__device__ __forceinline__ unsigned short f2bf(float f){
  unsigned int u = __float_as_uint(f);
  u = u + 0x7FFFu + ((u >> 16) & 1u);
  return (unsigned short)(u >> 16);
}
__device__ __forceinline__ float bf2f(unsigned short s){
  return __uint_as_float(((unsigned int)s) << 16);
}

// problem sizes: B=8 Q=16 KV=2048 NQ=NK=NV=H=512
#define KEYS_N   8388608
#define QG_BLOCKS 16              // qgemm blocks FIRST (start at t=0, hide under convert)
#define CONV_BLOCKS 4224          // 4096 keys + 128 wk
#define SCALE_2LOG2E 2.885390081777927f   // 2*log2(e): exp2(x*S) = exp(2x)

// workspace layout (bytes); total = 22,806,528
#define OFF_KEYS_BF   0u          // 16384x512 bf16
#define OFF_WK_BF     16777216u   // 512x512 bf16
#define OFF_EQB       17301504u   // 128x512 f32: exp2(S*q_part)
#define OFF_EPART     17563648u   // 4 x [8*2048*16] f32 partial logits
#define OFF_SC        21757952u   // 8x2048x16 f32 scores

// ---------------- K1: q-GEMM (blocks 0..15) ∥ convert (blocks 16..4239) ---
// qgemm: M=128 query rows x N=32 Wq rows, K=512, BK=32, f32 reg-staged with
// next-kt register prefetch (loads overlap write+sync+mfma).
__global__ __launch_bounds__(256) void k_convert(
    const float* __restrict__ keys, const float* __restrict__ W,
    const float* __restrict__ query,
    unsigned short* __restrict__ keys_bf, unsigned short* __restrict__ wk_bf,
    float* __restrict__ eqb)
{
  __shared__ short qg[128*32 + 32*32];     // 10 KB (qgemm branch only)
  if (blockIdx.x < QG_BLOCKS) {
    const int n0 = blockIdx.x * 32;
    const int tid = threadIdx.x;
    const int l = tid & 63, w = tid >> 6;
    short* A  = qg;                 // [128][32] swizzled
    short* Bs = qg + 4096;          // [32][32] swizzled
    const int sub = tid >> 3;       // 0..31
    const int c4  = (tid & 7) * 4;  // col within 32
    const int wm = w & 1, wn = w >> 1;
    const int fr = l & 15, fg = l >> 4;

    f32x4 acc[4];
    #pragma unroll
    for (int i = 0; i < 4; ++i) acc[i] = (f32x4){0.f,0.f,0.f,0.f};

    float4 a4[4], b4, a4n[4], b4n;
    #pragma unroll
    for (int m = 0; m < 4; ++m)
      a4[m] = *(const float4*)(query + (size_t)(m * 32 + sub) * 512 + c4);
    b4 = *(const float4*)(W + (size_t)(n0 + sub) * 1024 + c4);

    for (int kt = 0; kt < 16; ++kt) {
      if (kt < 15) {                 // issue next-kt loads early (overlap)
        const int k0 = (kt + 1) * 32;
        #pragma unroll
        for (int m = 0; m < 4; ++m)
          a4n[m] = *(const float4*)(query + (size_t)(m * 32 + sub) * 512 + k0 + c4);
        b4n = *(const float4*)(W + (size_t)(n0 + sub) * 1024 + k0 + c4);
      }
      __syncthreads();              // prior mfma reads done before overwrite
      #pragma unroll
      for (int m = 0; m < 4; ++m) {
        const int row = m * 32 + sub;
        const int o = row * 32 + (((c4 >> 3) ^ ((row >> 1) & 3)) << 3) + (c4 & 7);
        *(uint2*)&A[o] = make_uint2(pk2(a4[m].x, a4[m].y), pk2(a4[m].z, a4[m].w));
      }
      {
        const int o = sub * 32 + (((c4 >> 3) ^ ((sub >> 1) & 3)) << 3) + (c4 & 7);
        *(uint2*)&Bs[o] = make_uint2(pk2(b4.x, b4.y), pk2(b4.z, b4.w));
      }
      __syncthreads();
      bf16x8 af[4], bfv;
      #pragma unroll
      for (int i = 0; i < 4; ++i) {
        const int ar = wm*64 + i*16 + fr;
        af[i] = *(const bf16x8*)&A[ar*32 + ((fg ^ ((ar>>1)&3)) << 3)];
      }
      const int br = wn*16 + fr;
      bfv = *(const bf16x8*)&Bs[br*32 + ((fg ^ ((br>>1)&3)) << 3)];
      #pragma unroll
      for (int i = 0; i < 4; ++i)
        acc[i] = __builtin_amdgcn_mfma_f32_16x16x32_bf16(af[i], bfv, acc[i], 0, 0, 0);
      if (kt < 15) {
        #pragma unroll
        for (int m = 0; m < 4; ++m) a4[m] = a4n[m];
        b4 = b4n;
      }
    }
    const int gh = n0 + wn*16 + fr;
    #pragma unroll
    for (int i = 0; i < 4; ++i)
      #pragma unroll
      for (int r = 0; r < 4; ++r) {
        const int gm = wm*64 + i*16 + fg*4 + r;
        eqb[gm * 512 + gh] = exp2_f(acc[i][r] * SCALE_2LOG2E);
      }
    return;
  }
  // ---- convert path
  int idx = ((blockIdx.x - QG_BLOCKS) * 256 + threadIdx.x) * 8;
  const float* src;
  unsigned short* dst;
  if (idx < KEYS_N) { src = keys + idx; dst = keys_bf + idx; }
  else {
    int e = idx - KEYS_N;                    // wk[h][c]
    src = W + (size_t)(e >> 9) * 1024 + 512 + (e & 511);
    dst = wk_bf + e;
  }
  float4 a = *(const float4*)src;
  float4 b = *(const float4*)(src + 4);
  ushort8 o;
  o[0]=f2bf(a.x); o[1]=f2bf(a.y); o[2]=f2bf(a.z); o[3]=f2bf(a.w);
  o[4]=f2bf(b.x); o[5]=f2bf(b.y); o[6]=f2bf(b.z); o[7]=f2bf(b.w);
  *(ushort8*)dst = o;
}

// ---------------- K2: FUSED k-GEMM + energy, async dbuf (counted vmcnt) ---
// dbuf BK=64 staging 64KB (union ekbf 32KB) + eqs 8KB = 72KB -> 2 blocks/CU.
// Raw s_barrier + vmcnt(8): next tile's 8 global_load_lds stay in flight
// across the barrier (T4). eqs' 2 global loads are older than buf0's, so
// vmcnt(8) at kt=0 waits exactly eqs+buf0.
struct FusedSM {
  union {
    struct { short A[2][8192]; short B[2][8192]; } g;  // 64 KB
    unsigned short ekbf[128 * 128];                    // 32 KB
  } u;
  float eqs[16 * 128];                                 // 8 KB
};

__global__ __launch_bounds__(256, 2) void k_fused(
    const unsigned short* __restrict__ keys_bf, const unsigned short* __restrict__ wk_bf,
    const float* __restrict__ w_bias, const float* __restrict__ eqb,
    const float* __restrict__ vw, float* __restrict__ e_part)
{
  __shared__ FusedSM sm;
  const int tid = threadIdx.x;
  const int l = tid & 63, w = tid >> 6;
  const int by = blockIdx.x;              // 0..127 m-tile (128 k-rows)
  const int hc = blockIdx.y;              // 0..3 h-chunk
  const int h0 = hc * 128;
  const int b  = by >> 4;

  // stage eqs [16 q][128 h] (disjoint LDS region; its 2 vm-loads are the
  // oldest in the queue -> counted into vmcnt(8) at kt=0)
  {
    const int q = tid >> 4, c0 = (tid & 15) * 8;
    const float* src = eqb + (size_t)(b * 16 + q) * 512 + h0 + c0;
    *(float4*)&sm.eqs[q * 128 + c0]     = *(const float4*)src;
    *(float4*)&sm.eqs[q * 128 + c0 + 4] = *(const float4*)(src + 4);
  }

  const unsigned short* Aptr = keys_bf + (size_t)by * 128 * 512;
  const unsigned short* Bptr = wk_bf + (size_t)h0 * 512;

  const int srow = w * 32 + (l >> 3);
  const int scol = ((l & 7) ^ (l >> 3)) * 8;
  const int wm = w >> 1, wn = w & 1;
  const int fr = l & 15, fg = l >> 4;
  const int axk = fr & 7;

  f32x4 acc[4][4];
  #pragma unroll
  for (int i = 0; i < 4; ++i)
    #pragma unroll
    for (int j = 0; j < 4; ++j) acc[i][j] = (f32x4){0.f,0.f,0.f,0.f};

  auto stage = [&](int buf, int kt) {
    const int k0 = kt * 64;
    #pragma unroll
    for (int r = 0; r < 4; ++r) {
      GLL16(Aptr + (srow + r * 8) * 512 + k0 + scol, &sm.u.g.A[buf][w * 2048 + r * 512]);
      GLL16(Bptr + (srow + r * 8) * 512 + k0 + scol, &sm.u.g.B[buf][w * 2048 + r * 512]);
    }
  };
  auto compute = [&](int buf) {
    #pragma unroll
    for (int ks = 0; ks < 2; ++ks) {
      bf16x8 af[4], bfv[4];
      #pragma unroll
      for (int i = 0; i < 4; ++i) {
        af[i]  = *(const bf16x8*)&sm.u.g.A[buf][(wm*64 + i*16 + fr) * 64 + ((ks*4 + fg) ^ axk) * 8];
        bfv[i] = *(const bf16x8*)&sm.u.g.B[buf][(wn*64 + i*16 + fr) * 64 + ((ks*4 + fg) ^ axk) * 8];
      }
      #pragma unroll
      for (int i = 0; i < 4; ++i)
        #pragma unroll
        for (int j = 0; j < 4; ++j)
          acc[i][j] = __builtin_amdgcn_mfma_f32_16x16x32_bf16(af[i], bfv[j], acc[i][j], 0, 0, 0);
    }
  };

  stage(0, 0);
  #pragma unroll 1
  for (int kt = 0; kt < 8; ++kt) {
    if (kt < 7) {
      stage((kt + 1) & 1, kt + 1);     // prefetch stays in flight across barrier
      asm volatile("s_waitcnt vmcnt(8)" ::: "memory");
    } else {
      asm volatile("s_waitcnt vmcnt(0)" ::: "memory");
    }
    __builtin_amdgcn_sched_barrier(0);
    __builtin_amdgcn_s_barrier();        // buf[kt&1] staged for ALL waves
    __builtin_amdgcn_sched_barrier(0);
    compute(kt & 1);
    asm volatile("s_waitcnt lgkmcnt(0)" ::: "memory");
    __builtin_amdgcn_sched_barrier(0);
    __builtin_amdgcn_s_barrier();        // all reads of buf[kt&1] done
    __builtin_amdgcn_sched_barrier(0);
  }

  // all waves: acc -> ekbf (bf16), swizzled chunk' = (col>>3) ^ (row&15)
  #pragma unroll
  for (int j = 0; j < 4; ++j) {
    const int col = wn*64 + j*16 + fr;
    const float bias = w_bias[h0 + col];
    const int chunk = col >> 3, coff = col & 7;
    #pragma unroll
    for (int i = 0; i < 4; ++i)
      #pragma unroll
      for (int r = 0; r < 4; ++r) {
        const int row = wm*64 + i*16 + fg*4 + r;       // row&15 = fg*4+r
        const float ev = exp2_f((acc[i][j][r] + bias) * SCALE_2LOG2E);
        sm.u.ekbf[row * 128 + ((chunk ^ (fg*4 + r)) << 3) + coff] = f2bf(ev);
      }
  }
  // v weights (pre-scaled by -2); lane owns h {s*32+g*4+u, s*32+16+g*4+u}
  const int g = l & 3, kl = l >> 2;
  float vv[32];
  #pragma unroll
  for (int s = 0; s < 4; ++s) {
    const float4 a0 = *(const float4*)(vw + h0 + s*32 + g*4);
    const float4 a1 = *(const float4*)(vw + h0 + s*32 + 16 + g*4);
    vv[s*8+0]=-2.f*a0.x; vv[s*8+1]=-2.f*a0.y; vv[s*8+2]=-2.f*a0.z; vv[s*8+3]=-2.f*a0.w;
    vv[s*8+4]=-2.f*a1.x; vv[s*8+5]=-2.f*a1.y; vv[s*8+6]=-2.f*a1.z; vv[s*8+7]=-2.f*a1.w;
  }
  __syncthreads();

  // energy: wave w owns rows {w*32+kl, w*32+16+kl}; one eqs pass serves both
  {
    const int lr0 = w * 32 + kl;                 // lr0&15 = kl
    const int lr1 = lr0 + 16;                    // lr1&15 = kl (same ck)
    float ek0[32], ek1[32];
    #pragma unroll
    for (int s = 0; s < 4; ++s)
      #pragma unroll
      for (int hf = 0; hf < 2; ++hf) {
        const int ck = (4*s + 2*hf + (g >> 1)) ^ kl;
        const short4v v40 = *(const short4v*)&sm.u.ekbf[lr0 * 128 + (ck << 3) + (g & 1) * 4];
        const short4v v41 = *(const short4v*)&sm.u.ekbf[lr1 * 128 + (ck << 3) + (g & 1) * 4];
        #pragma unroll
        for (int u = 0; u < 4; ++u) {
          ek0[s*8 + hf*4 + u] = bf2f((unsigned short)v40[u]);
          ek1[s*8 + hf*4 + u] = bf2f((unsigned short)v41[u]);
        }
      }
    const size_t ep0 = (size_t)hc * 262144 + ((size_t)(by * 128 + lr0)) * 16;
    const size_t ep1 = (size_t)hc * 262144 + ((size_t)(by * 128 + lr1)) * 16;
    #pragma unroll 2
    for (int q = 0; q < 16; ++q) {
      float a00 = 0.f, a01 = 0.f, a10 = 0.f, a11 = 0.f;
      #pragma unroll
      for (int s = 0; s < 4; ++s) {
        const float* er = &sm.eqs[q * 128 + s * 32 + g * 4];
        const float4 E0 = *(const float4*)er;
        const float4 E1 = *(const float4*)(er + 16);
        a00 = fmaf(vv[s*8+0], rcp_f(fmaf(ek0[s*8+0], E0.x, 1.f)), a00);
        a01 = fmaf(vv[s*8+1], rcp_f(fmaf(ek0[s*8+1], E0.y, 1.f)), a01);
        a00 = fmaf(vv[s*8+2], rcp_f(fmaf(ek0[s*8+2], E0.z, 1.f)), a00);
        a01 = fmaf(vv[s*8+3], rcp_f(fmaf(ek0[s*8+3], E0.w, 1.f)), a01);
        a00 = fmaf(vv[s*8+4], rcp_f(fmaf(ek0[s*8+4], E1.x, 1.f)), a00);
        a01 = fmaf(vv[s*8+5], rcp_f(fmaf(ek0[s*8+5], E1.y, 1.f)), a01);
        a00 = fmaf(vv[s*8+6], rcp_f(fmaf(ek0[s*8+6], E1.z, 1.f)), a00);
        a01 = fmaf(vv[s*8+7], rcp_f(fmaf(ek0[s*8+7], E1.w, 1.f)), a01);
        a10 = fmaf(vv[s*8+0], rcp_f(fmaf(ek1[s*8+0], E0.x, 1.f)), a10);
        a11 = fmaf(vv[s*8+1], rcp_f(fmaf(ek1[s*8+1], E0.y, 1.f)), a11);
        a10 = fmaf(vv[s*8+2], rcp_f(fmaf(ek1[s*8+2], E0.z, 1.f)), a10);
        a11 = fmaf(vv[s*8+3], rcp_f(fmaf(ek1[s*8+3], E0.w, 1.f)), a11);
        a10 = fmaf(vv[s*8+4], rcp_f(fmaf(ek1[s*8+4], E1.x, 1.f)), a10);
        a11 = fmaf(vv[s*8+5], rcp_f(fmaf(ek1[s*8+5], E1.y, 1.f)), a11);
        a10 = fmaf(vv[s*8+6], rcp_f(fmaf(ek1[s*8+6], E1.z, 1.f)), a10);
        a11 = fmaf(vv[s*8+7], rcp_f(fmaf(ek1[s*8+7], E1.w, 1.f)), a11);
      }
      float r0 = a00 + a01;
      r0 += __shfl_xor(r0, 1, 64);
      r0 += __shfl_xor(r0, 2, 64);
      float r1 = a10 + a11;
      r1 += __shfl_xor(r1, 1, 64);
      r1 += __shfl_xor(r1, 2, 64);
      if (g == 0) { e_part[ep0 + q] = r0; e_part[ep1 + q] = r1; }
    }
  }
}

// ---------------- K3: softmax over k: sum 4 partials, normalize -----------
__global__ __launch_bounds__(256) void k_softmax(
    const float* __restrict__ e_part, float* __restrict__ sc)
{
  const int b = blockIdx.x >> 4, q = blockIdx.x & 15;
  const int base = b * 32768 + q;           // stride 16 over k
  const int tid = threadIdx.x;
  __shared__ float redm[4], reds[4];

  float vals[8];
  float mx = -1e30f;
  #pragma unroll
  for (int i = 0; i < 8; ++i) {
    const int x = base + (tid + i * 256) * 16;
    vals[i] = (e_part[x] + e_part[x + 262144]) + (e_part[x + 524288] + e_part[x + 786432]);
    mx = fmaxf(mx, vals[i]);
  }
  #pragma unroll
  for (int msk = 1; msk < 64; msk <<= 1) mx = fmaxf(mx, __shfl_xor(mx, msk, 64));
  if ((tid & 63) == 0) redm[tid >> 6] = mx;
  __syncthreads();
  mx = fmaxf(fmaxf(redm[0], redm[1]), fmaxf(redm[2], redm[3]));

  float ex[8], sum = 0.f;
  #pragma unroll
  for (int i = 0; i < 8; ++i) { ex[i] = __expf(vals[i] - mx); sum += ex[i]; }
  #pragma unroll
  for (int msk = 1; msk < 64; msk <<= 1) sum += __shfl_xor(sum, msk, 64);
  if ((tid & 63) == 0) reds[tid >> 6] = sum;
  __syncthreads();
  sum = reds[0] + reds[1] + reds[2] + reds[3];
  const float r = 1.f / sum;
  #pragma unroll
  for (int i = 0; i < 8; ++i) sc[base + (tid + i * 256) * 16] = ex[i] * r;
}

// ---------------- K4: single-pass PV -> out, 256 blocks x 512 thr ---------
__global__ __launch_bounds__(512) void k_pv(
    const float* __restrict__ values, const float* __restrict__ sc,
    float* __restrict__ out)
{
  __shared__ float lds[128 * 20];            // 10 KB (stride-20: 2-way max)
  const int tid = threadIdx.x;
  const int nc = blockIdx.x & 31, b = blockIdx.x >> 5;
  const int n = tid & 15, kg = tid >> 4;     // 32 kg x 16 n
  const int l = tid & 63, w = tid >> 6;      // 8 waves
  const int n0 = nc * 16;

  float acc[16];
  #pragma unroll
  for (int q = 0; q < 16; ++q) acc[q] = 0.f;

  for (int kc = 0; kc < 16; ++kc) {
    __syncthreads();
    {
      const float* ssrc = sc + (size_t)(b * 2048 + kc * 128) * 16;
      const int row = tid >> 2, c4 = (tid & 3) * 4;
      *(float4*)&lds[row * 20 + c4] = *(const float4*)&ssrc[row * 16 + c4];
    }
    __syncthreads();
    const float* vb = values + ((size_t)(b * 2048 + kc * 128 + kg * 4)) * 512 + n0 + n;
    #pragma unroll
    for (int k2 = 0; k2 < 4; ++k2) {
      const float v = vb[(size_t)k2 * 512];
      const float* sr = &lds[(kg * 4 + k2) * 20];
      #pragma unroll
      for (int qq = 0; qq < 4; ++qq) {
        const float4 s4 = *(const float4*)&sr[qq * 4];
        acc[qq*4+0] = fmaf(v, s4.x, acc[qq*4+0]);
        acc[qq*4+1] = fmaf(v, s4.y, acc[qq*4+1]);
        acc[qq*4+2] = fmaf(v, s4.z, acc[qq*4+2]);
        acc[qq*4+3] = fmaf(v, s4.w, acc[qq*4+3]);
      }
    }
  }
  // within-wave reduce (lanes l, l^16, l^32 share n)
  #pragma unroll
  for (int q = 0; q < 16; ++q) {
    acc[q] += __shfl_xor(acc[q], 16, 64);
    acc[q] += __shfl_xor(acc[q], 32, 64);
  }
  __syncthreads();
  if (l < 16) {
    #pragma unroll
    for (int q = 0; q < 16; ++q) lds[w * 256 + q * 16 + l] = acc[q];
  }
  __syncthreads();
  if (tid < 256) {
    const int q = tid >> 4, nn = tid & 15;
    float s = 0.f;
    #pragma unroll
    for (int w2 = 0; w2 < 8; ++w2) s += lds[w2 * 256 + q * 16 + nn];
    out[((size_t)(b * 16 + q)) * 512 + n0 + nn] = s;
  }
}

extern "C" void kernel_launch(void* const* d_in, const int* in_sizes, int n_in,
                              void* d_out, int out_size, void* d_ws, size_t ws_size,
                              hipStream_t stream)
{
  const float* query  = (const float*)d_in[0];
  const float* keys   = (const float*)d_in[1];
  const float* values = (const float*)d_in[2];
  const float* W      = (const float*)d_in[3];
  const float* w_bias = (const float*)d_in[4];
  const float* vw     = (const float*)d_in[5];
  // d_in[6] (v_bias) + sum_h v_h are (k)-constant logit shifts -> softmax-invariant.

  char* ws = (char*)d_ws;
  unsigned short* keys_bf = (unsigned short*)(ws + OFF_KEYS_BF);
  unsigned short* wk_bf   = (unsigned short*)(ws + OFF_WK_BF);
  float* eqb    = (float*)(ws + OFF_EQB);
  float* e_part = (float*)(ws + OFF_EPART);
  float* sc     = (float*)(ws + OFF_SC);

  hipLaunchKernelGGL(k_convert, dim3(QG_BLOCKS + CONV_BLOCKS), dim3(256), 0, stream,
                     keys, W, query, keys_bf, wk_bf, eqb);
  hipLaunchKernelGGL(k_fused, dim3(128, 4), dim3(256), 0, stream,
                     keys_bf, wk_bf, w_bias, eqb, vw, e_part);
  hipLaunchKernelGGL(k_softmax, dim3(128), dim3(256), 0, stream, e_part, sc);
  hipLaunchKernelGGL(k_pv, dim3(256), dim3(512), 0, stream, values, sc, (float*)d_out);
}